// Round 15
// baseline (162.021 us; speedup 1.0000x reference)
//
#include <hip/hip_runtime.h>
#include <hip/hip_fp16.h>
#include <hip/hip_bf16.h>

typedef short bf16x8 __attribute__((ext_vector_type(8)));
typedef float f32x4 __attribute__((ext_vector_type(4)));
typedef _Float16 f16x2 __attribute__((ext_vector_type(2)));

#define LGKM_FENCE() asm volatile("s_waitcnt lgkmcnt(0)" ::: "memory")
#define CAP 32

static __device__ __forceinline__ f16x2 as_f16x2(uint v) {
  union { uint u; f16x2 h; } c; c.u = v; return c.h;
}

static __device__ __forceinline__ float dot2acc(uint a, uint b, float c) {
#if __has_builtin(__builtin_amdgcn_fdot2)
  return __builtin_amdgcn_fdot2(as_f16x2(a), as_f16x2(b), c, false);
#else
  float2 af = __half22float2(*(const __half2*)&a);
  float2 bf = __half22float2(*(const __half2*)&b);
  return fmaf(af.x, bf.x, fmaf(af.y, bf.y, c));
#endif
}

// ---------------------------------------------------------------------------
// K1: per-node log_map (bf16 out) + gate softmax; tail block ranges do the
// W transpose AND the direct slot-scatter (no CSR pipeline).
// ---------------------------------------------------------------------------
__global__ __launch_bounds__(256) void k_tangent_gate(
    const float* __restrict__ x, const float* __restrict__ Wg,
    const float* __restrict__ bg, __hip_bfloat16* __restrict__ xtb,
    float* __restrict__ gate, const float* __restrict__ Wp,
    __hip_bfloat16* __restrict__ Wt, const int* __restrict__ row,
    const int* __restrict__ col, int* __restrict__ cnt,
    int* __restrict__ slots, int* __restrict__ ovf_cnt,
    int2* __restrict__ ovf, int N, int E) {
  int tb = (N + 3) >> 2;
  if ((int)blockIdx.x >= tb + 256) {
    int e = (blockIdx.x - tb - 256) * 256 + threadIdx.x;
    if (e < E) {
      int c = col[e];
      int p = atomicAdd(&cnt[c], 1);
      if (p < CAP) slots[(size_t)c * CAP + p] = row[e];
      else { int q = atomicAdd(ovf_cnt, 1); ovf[q] = make_int2(c, row[e]); }
    }
    return;
  }
  if ((int)blockIdx.x >= tb) {
    int idx = (blockIdx.x - tb) * 256 + threadIdx.x;
    if (idx < 512 * 128) {
      int n = idx >> 7, k = idx & 127;
      Wt[idx] = __float2bfloat16(Wp[(size_t)k * 512 + n]);
    }
    return;
  }
  int wid = (blockIdx.x * blockDim.x + threadIdx.x) >> 6;
  int lane = threadIdx.x & 63;
  if (wid >= N) return;

  const float* xr = x + (size_t)wid * 128;
  float2 xv = *(const float2*)(xr + lane * 2);
  xv.x = fminf(fmaxf(xv.x, -10000.f), 10000.f);
  xv.y = fminf(fmaxf(xv.y, -10000.f), 10000.f);

  float p = xv.x * xv.x + xv.y * xv.y;
  if (lane == 0) p -= 2.f * xv.x * xv.x;
  #pragma unroll
  for (int s = 32; s; s >>= 1) p += __shfl_xor(p, s);
  float x0 = __shfl(xv.x, 0);

  float denom = sqrtf(fmaxf(fabsf(p), 1e-12f));
  float cosd = fmaxf(x0 / denom, 1.0f + 1e-6f);
  float t = cosd - 1.0f;
  float coef = (t < 1e-3f)
      ? 1.0f - t * (1.f / 3.f) + t * t * (2.f / 15.f)
      : acoshf(cosd) * rsqrtf(t * (2.f + t));

  float2 o;
  o.x = coef * ((lane == 0) ? 2.0f * xv.x : xv.x);
  o.y = coef * xv.y;
  __hip_bfloat162 hb = __float22bfloat162_rn(make_float2(o.x, o.y));
  *(__hip_bfloat162*)(xtb + (size_t)wid * 128 + lane * 2) = hb;

  const float4 w0 = *(const float4*)(Wg + (size_t)(lane * 2) * 4);
  const float4 w1 = *(const float4*)(Wg + (size_t)(lane * 2 + 1) * 4);
  float g0 = o.x * w0.x + o.y * w1.x;
  float g1 = o.x * w0.y + o.y * w1.y;
  float g2 = o.x * w0.z + o.y * w1.z;
  float g3 = o.x * w0.w + o.y * w1.w;
  #pragma unroll
  for (int s = 32; s; s >>= 1) {
    g0 += __shfl_xor(g0, s); g1 += __shfl_xor(g1, s);
    g2 += __shfl_xor(g2, s); g3 += __shfl_xor(g3, s);
  }
  g0 += bg[0]; g1 += bg[1]; g2 += bg[2]; g3 += bg[3];
  float m = fmaxf(fmaxf(g0, g1), fmaxf(g2, g3));
  float e0 = expf(g0 - m), e1 = expf(g1 - m), e2 = expf(g2 - m), e3 = expf(g3 - m);
  float z = e0 + e1 + e2 + e3;
  if (lane == 0)
    *(float4*)(gate + (size_t)wid * 4) = make_float4(e0 / z, e1 / z, e2 / z, e3 / z);
}

// ---------------------------------------------------------------------------
// K2: u_hat via bf16 MFMA — B panel register-resident. TPB=4 spreads 782
// blocks across all CUs (TPB=8 left ~40% of CUs idle).
// ---------------------------------------------------------------------------
#define TPB 4
__global__ __launch_bounds__(256, 2) void k_uhat_mfma(
    const short* __restrict__ xtb, const float* __restrict__ gate,
    const short* __restrict__ Wt, const float* __restrict__ bp,
    __half* __restrict__ uh, int N, int ntiles) {
  int lane = threadIdx.x & 63;
  int wv = threadIdx.x >> 6;
  int ri = lane & 15, kg = lane >> 4;
  int c_lo = wv * 32;

  bf16x8 bfr[4][2][4];
  float bpv[4][2];
  #pragma unroll
  for (int p = 0; p < 4; ++p)
    #pragma unroll
    for (int n2 = 0; n2 < 2; ++n2) {
      int bcol = p * 128 + c_lo + n2 * 16 + ri;
      #pragma unroll
      for (int ks = 0; ks < 4; ++ks)
        bfr[p][n2][ks] = *(const bf16x8*)(Wt + (((size_t)bcol) << 7) + ks * 32 + kg * 8);
      bpv[p][n2] = bp[bcol];
    }

  int t0 = blockIdx.x * TPB;
  int t1 = t0 + TPB < ntiles ? t0 + TPB : ntiles;
  for (int t = t0; t < t1; ++t) {
    int m0 = t * 16;
    int r0 = m0 + ri;
    int c0 = (r0 < N) ? r0 : (N - 1);
    bf16x8 af[4];
    #pragma unroll
    for (int ks = 0; ks < 4; ++ks)
      af[ks] = *(const bf16x8*)(xtb + (((size_t)c0) << 7) + ks * 32 + kg * 8);

    int rb = m0 + kg * 4;
    float gg[4][4];
    #pragma unroll
    for (int q = 0; q < 4; ++q) {
      int rm = rb + q;
      bool ok = rm < N;
      const float* gr = gate + (size_t)(ok ? rm : 0) * 4;
      #pragma unroll
      for (int p = 0; p < 4; ++p) gg[q][p] = ok ? gr[p] : 0.f;
    }

    float fin[2][4];
    #pragma unroll
    for (int n2 = 0; n2 < 2; ++n2)
      #pragma unroll
      for (int q = 0; q < 4; ++q) fin[n2][q] = 0.f;

    #pragma unroll
    for (int p = 0; p < 4; ++p)
      #pragma unroll
      for (int n2 = 0; n2 < 2; ++n2) {
        f32x4 acc = {0.f, 0.f, 0.f, 0.f};
        #pragma unroll
        for (int ks = 0; ks < 4; ++ks)
          acc = __builtin_amdgcn_mfma_f32_16x16x32_bf16(af[ks], bfr[p][n2][ks], acc, 0, 0, 0);
        #pragma unroll
        for (int q = 0; q < 4; ++q)
          fin[n2][q] += gg[q][p] * (acc[q] + bpv[p][n2]);
      }

    #pragma unroll
    for (int n2 = 0; n2 < 2; ++n2) {
      int cn = c_lo + n2 * 16 + ri;
      #pragma unroll
      for (int q = 0; q < 4; ++q) {
        int rm = rb + q;
        if (rm < N) uh[(size_t)rm * 128 + cn] = __float2half_rn(fin[n2][q]);
      }
    }
  }
}

// ---------------------------------------------------------------------------
// K6: fused 3-iteration routing + squash + exp_map.
// r12's proven shell: ONE wave per node, 64-thread blocks, grid=N,
// launch_bounds(64,4) (VGPR 64, no spill). Rows from slots[j][*].
// Gather + round-0 sum merged into one chunked wave-uniform loop.
// ---------------------------------------------------------------------------
__global__ __launch_bounds__(64, 4) void k_route(
    const __half* __restrict__ uh, const float* __restrict__ bias,
    const int* __restrict__ cnt, const int* __restrict__ slots,
    const int* __restrict__ ovf_cnt, const int2* __restrict__ ovf,
    int* __restrict__ fbc, int* __restrict__ claim,
    int* __restrict__ fb_rows, float* __restrict__ fb_b,
    float* __restrict__ out, int N) {
  __shared__ __align__(16) uint ssw[64];  // s as half2 words
  int lane = threadIdx.x;
  int j = blockIdx.x;
  int deg = cnt[j];
  int d0 = lane * 2;

  if (deg == 0) {
    *(float2*)(out + (size_t)j * 128 + d0) =
        make_float2((lane == 0) ? 1.f : 0.f, 0.f);
    return;
  }

  float2 bia = *(const float2*)(bias + d0);
  float s0 = 0.f, s1 = 0.f;

  if (deg <= CAP) {
    const uint* uhw = (const uint*)uh;
    int myrow = (lane < deg) ? slots[(size_t)j * CAP + lane] : 0;

    int e = lane >> 1, h = lane & 1;
    // dot-layout gather: lane-pair (e,h) loads edge e's half-row
    int er = __shfl(myrow, (e < deg) ? e : 0);
    const uint4* up = (const uint4*)(uhw + (((size_t)(uint)er) << 6) + h * 32);
    uint4 ud[8];
    #pragma unroll
    for (int k4 = 0; k4 < 8; ++k4) ud[k4] = up[k4];

    // dim-layout gather + round-0 sum, merged chunked loop
    uint g[CAP];
    float a0 = 0.f, a1 = 0.f;
    #pragma unroll
    for (int c = 0; c < CAP; c += 8) {
      if (c < deg) {   // wave-uniform branch
        #pragma unroll
        for (int k = 0; k < 8; ++k) {
          int i = c + k;
          int rr = __builtin_amdgcn_readlane(myrow, i);
          uint v = uhw[(((size_t)(uint)rr) << 6) + lane];
          g[i] = (i < deg) ? v : 0u;
          float2 uf = __half22float2(*(const __half2*)&g[i]);
          a0 += uf.x; a1 += uf.y;
        }
      }
    }

    float invd = 1.f / (float)deg;
    s0 = a0 * invd + bia.x;
    s1 = a1 * invd + bia.y;
    {
      float ns = s0 * s0 + s1 * s1;
      #pragma unroll
      for (int s = 32; s; s >>= 1) ns += __shfl_xor(ns, s);
      float scale = (ns / (1.f + ns)) * rsqrtf(ns + 1e-9f);
      s0 *= scale; s1 *= scale;
    }

    const uint* ssw_h = &ssw[h * 32];
    bool act = (e < deg);
    float b = 0.f;

    #pragma unroll
    for (int r = 0; r < 2; ++r) {
      // publish s (f16)
      __half2 sh2 = __floats2half2_rn(s0, s1);
      ssw[lane] = *(const uint*)&sh2;
      LGKM_FENCE();

      // per-edge dot from registers: 8 b128 s-reads + 32 fdot2
      float acc0 = 0.f, acc1 = 0.f;
      #pragma unroll
      for (int k4 = 0; k4 < 8; ++k4) {
        uint4 sw = *(const uint4*)&ssw_h[k4 * 4];
        acc0 = dot2acc(ud[k4].x, sw.x, acc0);
        acc1 = dot2acc(ud[k4].y, sw.y, acc1);
        acc0 = dot2acc(ud[k4].z, sw.z, acc0);
        acc1 = dot2acc(ud[k4].w, sw.w, acc1);
      }
      float acc = acc0 + acc1;
      acc += __shfl_xor(acc, 1);
      b += acc;
      float eb = act ? __expf(b) : 0.f;

      // weighted sum: chunked readlane, dual accumulators
      float z0 = 0.f, z1 = 0.f, wa0 = 0.f, wa1 = 0.f, wb0 = 0.f, wb1 = 0.f;
      #pragma unroll
      for (int c = 0; c < CAP; c += 8) {
        if (c < deg) {
          #pragma unroll
          for (int k = 0; k < 8; ++k) {
            int i = c + k;
            float ev = __uint_as_float(
                __builtin_amdgcn_readlane(__float_as_uint(eb), 2 * i));
            float2 uf = __half22float2(*(const __half2*)&g[i]);
            if (k & 1) { z1 += ev; wa1 = fmaf(ev, uf.x, wa1); wb1 = fmaf(ev, uf.y, wb1); }
            else       { z0 += ev; wa0 = fmaf(ev, uf.x, wa0); wb0 = fmaf(ev, uf.y, wb0); }
          }
        }
      }
      float z = z0 + z1;
      float invz = 1.f / z;
      s0 = (wa0 + wa1) * invz + bia.x;
      s1 = (wb0 + wb1) * invz + bia.y;
      float ns = s0 * s0 + s1 * s1;
      #pragma unroll
      for (int s = 32; s; s >>= 1) ns += __shfl_xor(ns, s);
      float scale = (ns / (1.f + ns)) * rsqrtf(ns + 1e-9f);
      s0 *= scale; s1 *= scale;
    }
  } else {
    // fallback (deg > CAP, ~never): collect rows from slots + overflow list
    int base = 0;
    if (lane == 0) base = atomicAdd(claim, deg);
    base = __shfl(base, 0);
    int* mr = fb_rows + base;
    float* b = fb_b + base;
    if (lane < CAP) mr[lane] = slots[(size_t)j * CAP + lane];
    int novf = *ovf_cnt;
    for (int t = lane; t < novf; t += 64) {
      int2 ov = ovf[t];
      if (ov.x == j) {
        int p = atomicAdd(&fbc[j], 1);
        mr[CAP + p] = ov.y;
      }
    }
    asm volatile("s_waitcnt vmcnt(0)" ::: "memory");

    const __half2* uh2 = (const __half2*)uh;
    for (int i = lane; i < deg; i += 64) atomicExch(&b[i], 0.f);
    asm volatile("s_waitcnt vmcnt(0)" ::: "memory");

    for (int r = 0; r < 3; ++r) {
      float mx = -3.4e38f;
      for (int i = lane; i < deg; i += 64)
        mx = fmaxf(mx, atomicAdd(&b[i], 0.f));
      #pragma unroll
      for (int s = 32; s; s >>= 1) mx = fmaxf(mx, __shfl_xor(mx, s));
      float z = 0.f;
      for (int i = lane; i < deg; i += 64) z += expf(atomicAdd(&b[i], 0.f) - mx);
      #pragma unroll
      for (int s = 32; s; s >>= 1) z += __shfl_xor(z, s);
      float invz = 1.f / z;

      s0 = 0.f; s1 = 0.f;
      for (int i = 0; i < deg; ++i) {
        float c = expf(atomicAdd(&b[i], 0.f) - mx) * invz;
        int rr = mr[i];
        float2 uf = __half22float2(uh2[(((size_t)rr) << 6) + lane]);
        s0 = fmaf(c, uf.x, s0);
        s1 = fmaf(c, uf.y, s1);
      }
      s0 += bia.x; s1 += bia.y;

      float ns = s0 * s0 + s1 * s1;
      #pragma unroll
      for (int s = 32; s; s >>= 1) ns += __shfl_xor(ns, s);
      float scale = (ns / (1.f + ns)) * rsqrtf(ns + 1e-9f);
      s0 *= scale; s1 *= scale;

      if (r < 2) {
        for (int i = 0; i < deg; ++i) {
          int rr = mr[i];
          float2 uf = __half22float2(uh2[(((size_t)rr) << 6) + lane]);
          float pp = s0 * uf.x + s1 * uf.y;
          #pragma unroll
          for (int s = 32; s; s >>= 1) pp += __shfl_xor(pp, s);
          if (lane == 0) atomicAdd(&b[i], pp);
        }
        asm volatile("s_waitcnt vmcnt(0)" ::: "memory");
      }
    }
  }

  // exp_map(s, ref)
  float pn = s0 * s0 + s1 * s1;
  if (lane == 0) pn -= 2.f * s0 * s0;
  #pragma unroll
  for (int s = 32; s; s >>= 1) pn += __shfl_xor(pn, s);
  float vn = fminf(sqrtf(fabsf(pn) + 1e-12f), 10.f);
  float sh = sinhf(vn) / vn;
  float ov0 = sh * s0 + ((lane == 0) ? coshf(vn) : 0.f);
  float ov1 = sh * s1;
  *(float2*)(out + (size_t)j * 128 + d0) = make_float2(ov0, ov1);
}

// ---------------------------------------------------------------------------
extern "C" void kernel_launch(void* const* d_in, const int* in_sizes, int n_in,
                              void* d_out, int out_size, void* d_ws, size_t ws_size,
                              hipStream_t stream) {
  const float* x    = (const float*)d_in[0];
  const int*   ei   = (const int*)d_in[1];
  const float* Wp   = (const float*)d_in[2];
  const float* bp   = (const float*)d_in[3];
  const float* Wg   = (const float*)d_in[4];
  const float* bg   = (const float*)d_in[5];
  const float* bias = (const float*)d_in[6];
  float* out = (float*)d_out;

  int N = in_sizes[0] / 128;
  int E = in_sizes[1] / 2;
  const int* row = ei;
  const int* col = ei + E;

  __hip_bfloat16* xtb = (__hip_bfloat16*)d_ws;                  // N*128 bf16
  __half* uhh = (__half*)(xtb + (size_t)N * 128);               // N*128 f16
  float* gate = (float*)(uhh + (size_t)N * 128);                // N*4 f32
  __hip_bfloat16* Wt = (__hip_bfloat16*)(gate + (size_t)N * 4); // 512*128 bf16
  int* cnt = (int*)(Wt + 512 * 128);                            // N
  int* fbc = cnt + N;                                           // N
  int* claim = fbc + N;                                         // 1
  int* ovf_cnt = claim + 1;                                     // 1
  int* slots = ovf_cnt + 1;                                     // N*CAP
  int2* ovf = (int2*)(slots + (size_t)N * CAP);                 // E int2
  int* fb_rows = (int*)(ovf + E);                               // E
  float* fb_b = (float*)(fb_rows + E);                          // E

  int tb = (N + 3) / 4;
  int hb = (E + 255) / 256;
  int ntiles = (N + 15) / 16;
  (void)hipMemsetAsync(cnt, 0, ((size_t)2 * N + 2) * sizeof(int), stream);
  k_tangent_gate<<<tb + 256 + hb, 256, 0, stream>>>(
      x, Wg, bg, xtb, gate, Wp, Wt, row, col, cnt, slots, ovf_cnt, ovf, N, E);
  k_uhat_mfma<<<(ntiles + TPB - 1) / TPB, 256, 0, stream>>>(
      (const short*)xtb, gate, (const short*)Wt, bp, uhh, N, ntiles);
  k_route<<<N, 64, 0, stream>>>(
      uhh, bias, cnt, slots, ovf_cnt, ovf, fbc, claim, fb_rows, fb_b, out, N);
}

// Round 16
// 157.139 us; speedup vs baseline: 1.0311x; 1.0311x over previous
//
#include <hip/hip_runtime.h>
#include <hip/hip_fp16.h>
#include <hip/hip_bf16.h>

typedef short bf16x8 __attribute__((ext_vector_type(8)));
typedef float f32x4 __attribute__((ext_vector_type(4)));
typedef _Float16 f16x2 __attribute__((ext_vector_type(2)));

#define LGKM_FENCE() asm volatile("s_waitcnt lgkmcnt(0)" ::: "memory")
#define CAP 32

static __device__ __forceinline__ f16x2 as_f16x2(uint v) {
  union { uint u; f16x2 h; } c; c.u = v; return c.h;
}

static __device__ __forceinline__ float dot2acc(uint a, uint b, float c) {
#if __has_builtin(__builtin_amdgcn_fdot2)
  return __builtin_amdgcn_fdot2(as_f16x2(a), as_f16x2(b), c, false);
#else
  float2 af = __half22float2(*(const __half2*)&a);
  float2 bf = __half22float2(*(const __half2*)&b);
  return fmaf(af.x, bf.x, fmaf(af.y, bf.y, c));
#endif
}

// ---------------------------------------------------------------------------
// K1: per-node log_map (bf16 out) + gate softmax; tail block ranges do the
// W transpose AND the direct slot-scatter (no CSR pipeline).
// ---------------------------------------------------------------------------
__global__ __launch_bounds__(256) void k_tangent_gate(
    const float* __restrict__ x, const float* __restrict__ Wg,
    const float* __restrict__ bg, __hip_bfloat16* __restrict__ xtb,
    float* __restrict__ gate, const float* __restrict__ Wp,
    __hip_bfloat16* __restrict__ Wt, const int* __restrict__ row,
    const int* __restrict__ col, int* __restrict__ cnt,
    int* __restrict__ slots, int* __restrict__ ovf_cnt,
    int2* __restrict__ ovf, int N, int E) {
  int tb = (N + 3) >> 2;
  if ((int)blockIdx.x >= tb + 256) {
    // slot-scatter range: 2 edges per thread
    int e0 = ((blockIdx.x - tb - 256) * 256 + threadIdx.x) * 2;
    #pragma unroll
    for (int k = 0; k < 2; ++k) {
      int e = e0 + k;
      if (e < E) {
        int c = col[e];
        int p = atomicAdd(&cnt[c], 1);
        if (p < CAP) slots[(size_t)c * CAP + p] = row[e];
        else { int q = atomicAdd(ovf_cnt, 1); ovf[q] = make_int2(c, row[e]); }
      }
    }
    return;
  }
  if ((int)blockIdx.x >= tb) {
    int idx = (blockIdx.x - tb) * 256 + threadIdx.x;
    if (idx < 512 * 128) {
      int n = idx >> 7, k = idx & 127;
      Wt[idx] = __float2bfloat16(Wp[(size_t)k * 512 + n]);
    }
    return;
  }
  int wid = (blockIdx.x * blockDim.x + threadIdx.x) >> 6;
  int lane = threadIdx.x & 63;
  if (wid >= N) return;

  const float* xr = x + (size_t)wid * 128;
  float2 xv = *(const float2*)(xr + lane * 2);
  xv.x = fminf(fmaxf(xv.x, -10000.f), 10000.f);
  xv.y = fminf(fmaxf(xv.y, -10000.f), 10000.f);

  float p = xv.x * xv.x + xv.y * xv.y;
  if (lane == 0) p -= 2.f * xv.x * xv.x;
  #pragma unroll
  for (int s = 32; s; s >>= 1) p += __shfl_xor(p, s);
  float x0 = __shfl(xv.x, 0);

  float denom = sqrtf(fmaxf(fabsf(p), 1e-12f));
  float cosd = fmaxf(x0 / denom, 1.0f + 1e-6f);
  float t = cosd - 1.0f;
  float coef = (t < 1e-3f)
      ? 1.0f - t * (1.f / 3.f) + t * t * (2.f / 15.f)
      : acoshf(cosd) * rsqrtf(t * (2.f + t));

  float2 o;
  o.x = coef * ((lane == 0) ? 2.0f * xv.x : xv.x);
  o.y = coef * xv.y;
  __hip_bfloat162 hb = __float22bfloat162_rn(make_float2(o.x, o.y));
  *(__hip_bfloat162*)(xtb + (size_t)wid * 128 + lane * 2) = hb;

  const float4 w0 = *(const float4*)(Wg + (size_t)(lane * 2) * 4);
  const float4 w1 = *(const float4*)(Wg + (size_t)(lane * 2 + 1) * 4);
  float g0 = o.x * w0.x + o.y * w1.x;
  float g1 = o.x * w0.y + o.y * w1.y;
  float g2 = o.x * w0.z + o.y * w1.z;
  float g3 = o.x * w0.w + o.y * w1.w;
  #pragma unroll
  for (int s = 32; s; s >>= 1) {
    g0 += __shfl_xor(g0, s); g1 += __shfl_xor(g1, s);
    g2 += __shfl_xor(g2, s); g3 += __shfl_xor(g3, s);
  }
  g0 += bg[0]; g1 += bg[1]; g2 += bg[2]; g3 += bg[3];
  float m = fmaxf(fmaxf(g0, g1), fmaxf(g2, g3));
  float e0 = expf(g0 - m), e1 = expf(g1 - m), e2 = expf(g2 - m), e3 = expf(g3 - m);
  float z = e0 + e1 + e2 + e3;
  if (lane == 0)
    *(float4*)(gate + (size_t)wid * 4) = make_float4(e0 / z, e1 / z, e2 / z, e3 / z);
}

// ---------------------------------------------------------------------------
// K2: u_hat via bf16 MFMA — B panel register-resident, TPB=4.
// ---------------------------------------------------------------------------
#define TPB 4
__global__ __launch_bounds__(256, 2) void k_uhat_mfma(
    const short* __restrict__ xtb, const float* __restrict__ gate,
    const short* __restrict__ Wt, const float* __restrict__ bp,
    __half* __restrict__ uh, int N, int ntiles) {
  int lane = threadIdx.x & 63;
  int wv = threadIdx.x >> 6;
  int ri = lane & 15, kg = lane >> 4;
  int c_lo = wv * 32;

  bf16x8 bfr[4][2][4];
  float bpv[4][2];
  #pragma unroll
  for (int p = 0; p < 4; ++p)
    #pragma unroll
    for (int n2 = 0; n2 < 2; ++n2) {
      int bcol = p * 128 + c_lo + n2 * 16 + ri;
      #pragma unroll
      for (int ks = 0; ks < 4; ++ks)
        bfr[p][n2][ks] = *(const bf16x8*)(Wt + (((size_t)bcol) << 7) + ks * 32 + kg * 8);
      bpv[p][n2] = bp[bcol];
    }

  int t0 = blockIdx.x * TPB;
  int t1 = t0 + TPB < ntiles ? t0 + TPB : ntiles;
  for (int t = t0; t < t1; ++t) {
    int m0 = t * 16;
    int r0 = m0 + ri;
    int c0 = (r0 < N) ? r0 : (N - 1);
    bf16x8 af[4];
    #pragma unroll
    for (int ks = 0; ks < 4; ++ks)
      af[ks] = *(const bf16x8*)(xtb + (((size_t)c0) << 7) + ks * 32 + kg * 8);

    int rb = m0 + kg * 4;
    float gg[4][4];
    #pragma unroll
    for (int q = 0; q < 4; ++q) {
      int rm = rb + q;
      bool ok = rm < N;
      const float* gr = gate + (size_t)(ok ? rm : 0) * 4;
      #pragma unroll
      for (int p = 0; p < 4; ++p) gg[q][p] = ok ? gr[p] : 0.f;
    }

    float fin[2][4];
    #pragma unroll
    for (int n2 = 0; n2 < 2; ++n2)
      #pragma unroll
      for (int q = 0; q < 4; ++q) fin[n2][q] = 0.f;

    #pragma unroll
    for (int p = 0; p < 4; ++p)
      #pragma unroll
      for (int n2 = 0; n2 < 2; ++n2) {
        f32x4 acc = {0.f, 0.f, 0.f, 0.f};
        #pragma unroll
        for (int ks = 0; ks < 4; ++ks)
          acc = __builtin_amdgcn_mfma_f32_16x16x32_bf16(af[ks], bfr[p][n2][ks], acc, 0, 0, 0);
        #pragma unroll
        for (int q = 0; q < 4; ++q)
          fin[n2][q] += gg[q][p] * (acc[q] + bpv[p][n2]);
      }

    #pragma unroll
    for (int n2 = 0; n2 < 2; ++n2) {
      int cn = c_lo + n2 * 16 + ri;
      #pragma unroll
      for (int q = 0; q < 4; ++q) {
        int rm = rb + q;
        if (rm < N) uh[(size_t)rm * 128 + cn] = __float2half_rn(fin[n2][q]);
      }
    }
  }
}

// ---------------------------------------------------------------------------
// K6: fused 3-iteration routing + squash + exp_map.
// r12's proven shell AND loop structure: ONE wave per node, 64-thread
// blocks, grid=N, (64,4). Gather loop SEPARATE from accumulation loop
// (loads issue back-to-back per chunk; consumption deferred — G7).
// ---------------------------------------------------------------------------
__global__ __launch_bounds__(64, 4) void k_route(
    const __half* __restrict__ uh, const float* __restrict__ bias,
    const int* __restrict__ cnt, const int* __restrict__ slots,
    const int* __restrict__ ovf_cnt, const int2* __restrict__ ovf,
    int* __restrict__ fbc, int* __restrict__ claim,
    int* __restrict__ fb_rows, float* __restrict__ fb_b,
    float* __restrict__ out, int N) {
  __shared__ __align__(16) uint ssw[64];  // s as half2 words
  int lane = threadIdx.x;
  int j = blockIdx.x;
  int deg = cnt[j];
  int d0 = lane * 2;

  if (deg == 0) {
    *(float2*)(out + (size_t)j * 128 + d0) =
        make_float2((lane == 0) ? 1.f : 0.f, 0.f);
    return;
  }

  float2 bia = *(const float2*)(bias + d0);
  float s0 = 0.f, s1 = 0.f;

  if (deg <= CAP) {
    const uint* uhw = (const uint*)uh;
    int myrow = (lane < deg) ? slots[(size_t)j * CAP + lane] : 0;

    int e = lane >> 1, h = lane & 1;
    // dot-layout gather: lane-pair (e,h) loads edge e's half-row
    int er = __shfl(myrow, (e < deg) ? e : 0);
    const uint4* up = (const uint4*)(uhw + (((size_t)(uint)er) << 6) + h * 32);
    uint4 ud[8];
    #pragma unroll
    for (int k4 = 0; k4 < 8; ++k4) ud[k4] = up[k4];

    // dim-layout gather: chunked by 8, loads only (issue back-to-back)
    uint g[CAP];
    #pragma unroll
    for (int c = 0; c < CAP; c += 8) {
      if (c < deg) {   // wave-uniform branch
        #pragma unroll
        for (int k = 0; k < 8; ++k) {
          int i = c + k;
          int rr = __builtin_amdgcn_readlane(myrow, i);
          uint v = uhw[(((size_t)(uint)rr) << 6) + lane];
          g[i] = (i < deg) ? v : 0u;
        }
      }
    }

    // round-0 sum (c = 1/deg exactly) — separate consumption loop
    float a0 = 0.f, a1 = 0.f;
    #pragma unroll
    for (int c = 0; c < CAP; c += 8) {
      if (c < deg) {
        #pragma unroll
        for (int k = 0; k < 8; ++k) {
          int i = c + k;
          float2 uf = __half22float2(*(const __half2*)&g[i]);
          a0 += uf.x; a1 += uf.y;
        }
      }
    }

    float invd = 1.f / (float)deg;
    s0 = a0 * invd + bia.x;
    s1 = a1 * invd + bia.y;
    {
      float ns = s0 * s0 + s1 * s1;
      #pragma unroll
      for (int s = 32; s; s >>= 1) ns += __shfl_xor(ns, s);
      float scale = (ns / (1.f + ns)) * rsqrtf(ns + 1e-9f);
      s0 *= scale; s1 *= scale;
    }

    const uint* ssw_h = &ssw[h * 32];
    bool act = (e < deg);
    float b = 0.f;

    #pragma unroll
    for (int r = 0; r < 2; ++r) {
      // publish s (f16)
      __half2 sh2 = __floats2half2_rn(s0, s1);
      ssw[lane] = *(const uint*)&sh2;
      LGKM_FENCE();

      // per-edge dot from registers: 8 b128 s-reads + 32 fdot2
      float acc0 = 0.f, acc1 = 0.f;
      #pragma unroll
      for (int k4 = 0; k4 < 8; ++k4) {
        uint4 sw = *(const uint4*)&ssw_h[k4 * 4];
        acc0 = dot2acc(ud[k4].x, sw.x, acc0);
        acc1 = dot2acc(ud[k4].y, sw.y, acc1);
        acc0 = dot2acc(ud[k4].z, sw.z, acc0);
        acc1 = dot2acc(ud[k4].w, sw.w, acc1);
      }
      float acc = acc0 + acc1;
      acc += __shfl_xor(acc, 1);
      b += acc;
      float eb = act ? __expf(b) : 0.f;

      // weighted sum: chunked readlane, dual accumulators
      float z0 = 0.f, z1 = 0.f, wa0 = 0.f, wa1 = 0.f, wb0 = 0.f, wb1 = 0.f;
      #pragma unroll
      for (int c = 0; c < CAP; c += 8) {
        if (c < deg) {
          #pragma unroll
          for (int k = 0; k < 8; ++k) {
            int i = c + k;
            float ev = __uint_as_float(
                __builtin_amdgcn_readlane(__float_as_uint(eb), 2 * i));
            float2 uf = __half22float2(*(const __half2*)&g[i]);
            if (k & 1) { z1 += ev; wa1 = fmaf(ev, uf.x, wa1); wb1 = fmaf(ev, uf.y, wb1); }
            else       { z0 += ev; wa0 = fmaf(ev, uf.x, wa0); wb0 = fmaf(ev, uf.y, wb0); }
          }
        }
      }
      float z = z0 + z1;
      float invz = 1.f / z;
      s0 = (wa0 + wa1) * invz + bia.x;
      s1 = (wb0 + wb1) * invz + bia.y;
      float ns = s0 * s0 + s1 * s1;
      #pragma unroll
      for (int s = 32; s; s >>= 1) ns += __shfl_xor(ns, s);
      float scale = (ns / (1.f + ns)) * rsqrtf(ns + 1e-9f);
      s0 *= scale; s1 *= scale;
    }
  } else {
    // fallback (deg > CAP, ~never): collect rows from slots + overflow list
    int base = 0;
    if (lane == 0) base = atomicAdd(claim, deg);
    base = __shfl(base, 0);
    int* mr = fb_rows + base;
    float* b = fb_b + base;
    if (lane < CAP) mr[lane] = slots[(size_t)j * CAP + lane];
    int novf = *ovf_cnt;
    for (int t = lane; t < novf; t += 64) {
      int2 ov = ovf[t];
      if (ov.x == j) {
        int p = atomicAdd(&fbc[j], 1);
        mr[CAP + p] = ov.y;
      }
    }
    asm volatile("s_waitcnt vmcnt(0)" ::: "memory");

    const __half2* uh2 = (const __half2*)uh;
    for (int i = lane; i < deg; i += 64) atomicExch(&b[i], 0.f);
    asm volatile("s_waitcnt vmcnt(0)" ::: "memory");

    for (int r = 0; r < 3; ++r) {
      float mx = -3.4e38f;
      for (int i = lane; i < deg; i += 64)
        mx = fmaxf(mx, atomicAdd(&b[i], 0.f));
      #pragma unroll
      for (int s = 32; s; s >>= 1) mx = fmaxf(mx, __shfl_xor(mx, s));
      float z = 0.f;
      for (int i = lane; i < deg; i += 64) z += expf(atomicAdd(&b[i], 0.f) - mx);
      #pragma unroll
      for (int s = 32; s; s >>= 1) z += __shfl_xor(z, s);
      float invz = 1.f / z;

      s0 = 0.f; s1 = 0.f;
      for (int i = 0; i < deg; ++i) {
        float c = expf(atomicAdd(&b[i], 0.f) - mx) * invz;
        int rr = mr[i];
        float2 uf = __half22float2(uh2[(((size_t)rr) << 6) + lane]);
        s0 = fmaf(c, uf.x, s0);
        s1 = fmaf(c, uf.y, s1);
      }
      s0 += bia.x; s1 += bia.y;

      float ns = s0 * s0 + s1 * s1;
      #pragma unroll
      for (int s = 32; s; s >>= 1) ns += __shfl_xor(ns, s);
      float scale = (ns / (1.f + ns)) * rsqrtf(ns + 1e-9f);
      s0 *= scale; s1 *= scale;

      if (r < 2) {
        for (int i = 0; i < deg; ++i) {
          int rr = mr[i];
          float2 uf = __half22float2(uh2[(((size_t)rr) << 6) + lane]);
          float pp = s0 * uf.x + s1 * uf.y;
          #pragma unroll
          for (int s = 32; s; s >>= 1) pp += __shfl_xor(pp, s);
          if (lane == 0) atomicAdd(&b[i], pp);
        }
        asm volatile("s_waitcnt vmcnt(0)" ::: "memory");
      }
    }
  }

  // exp_map(s, ref)
  float pn = s0 * s0 + s1 * s1;
  if (lane == 0) pn -= 2.f * s0 * s0;
  #pragma unroll
  for (int s = 32; s; s >>= 1) pn += __shfl_xor(pn, s);
  float vn = fminf(sqrtf(fabsf(pn) + 1e-12f), 10.f);
  float sh = sinhf(vn) / vn;
  float ov0 = sh * s0 + ((lane == 0) ? coshf(vn) : 0.f);
  float ov1 = sh * s1;
  *(float2*)(out + (size_t)j * 128 + d0) = make_float2(ov0, ov1);
}

// ---------------------------------------------------------------------------
extern "C" void kernel_launch(void* const* d_in, const int* in_sizes, int n_in,
                              void* d_out, int out_size, void* d_ws, size_t ws_size,
                              hipStream_t stream) {
  const float* x    = (const float*)d_in[0];
  const int*   ei   = (const int*)d_in[1];
  const float* Wp   = (const float*)d_in[2];
  const float* bp   = (const float*)d_in[3];
  const float* Wg   = (const float*)d_in[4];
  const float* bg   = (const float*)d_in[5];
  const float* bias = (const float*)d_in[6];
  float* out = (float*)d_out;

  int N = in_sizes[0] / 128;
  int E = in_sizes[1] / 2;
  const int* row = ei;
  const int* col = ei + E;

  __hip_bfloat16* xtb = (__hip_bfloat16*)d_ws;                  // N*128 bf16
  __half* uhh = (__half*)(xtb + (size_t)N * 128);               // N*128 f16
  float* gate = (float*)(uhh + (size_t)N * 128);                // N*4 f32
  __hip_bfloat16* Wt = (__hip_bfloat16*)(gate + (size_t)N * 4); // 512*128 bf16
  int* cnt = (int*)(Wt + 512 * 128);                            // N
  int* fbc = cnt + N;                                           // N
  int* claim = fbc + N;                                         // 1
  int* ovf_cnt = claim + 1;                                     // 1
  int* slots = ovf_cnt + 1;                                     // N*CAP
  int2* ovf = (int2*)(slots + (size_t)N * CAP);                 // E int2
  int* fb_rows = (int*)(ovf + E);                               // E
  float* fb_b = (float*)(fb_rows + E);                          // E

  int tb = (N + 3) / 4;
  int hb = (E + 511) / 512;
  int ntiles = (N + 15) / 16;
  (void)hipMemsetAsync(cnt, 0, ((size_t)2 * N + 2) * sizeof(int), stream);
  k_tangent_gate<<<tb + 256 + hb, 256, 0, stream>>>(
      x, Wg, bg, xtb, gate, Wp, Wt, row, col, cnt, slots, ovf_cnt, ovf, N, E);
  k_uhat_mfma<<<(ntiles + TPB - 1) / TPB, 256, 0, stream>>>(
      (const short*)xtb, gate, (const short*)Wt, bp, uhh, N, ntiles);
  k_route<<<N, 64, 0, stream>>>(
      uhh, bias, cnt, slots, ovf_cnt, ovf, fbc, claim, fb_rows, fb_b, out, N);
}

// Round 17
// 152.492 us; speedup vs baseline: 1.0625x; 1.0305x over previous
//
#include <hip/hip_runtime.h>
#include <hip/hip_fp16.h>
#include <hip/hip_bf16.h>

typedef short bf16x8 __attribute__((ext_vector_type(8)));
typedef float f32x4 __attribute__((ext_vector_type(4)));
typedef _Float16 f16x2 __attribute__((ext_vector_type(2)));

#define LGKM_FENCE() asm volatile("s_waitcnt lgkmcnt(0)" ::: "memory")
#define CAP 32

static __device__ __forceinline__ f16x2 as_f16x2(uint v) {
  union { uint u; f16x2 h; } c; c.u = v; return c.h;
}

static __device__ __forceinline__ float dot2acc(uint a, uint b, float c) {
#if __has_builtin(__builtin_amdgcn_fdot2)
  return __builtin_amdgcn_fdot2(as_f16x2(a), as_f16x2(b), c, false);
#else
  float2 af = __half22float2(*(const __half2*)&a);
  float2 bf = __half22float2(*(const __half2*)&b);
  return fmaf(af.x, bf.x, fmaf(af.y, bf.y, c));
#endif
}

// ---------------------------------------------------------------------------
// K1: per-node log_map (bf16 out) + gate softmax; tail range: W transpose.
// (slot-scatter moved to k_uhat's grid — off uhat's critical path)
// ---------------------------------------------------------------------------
__global__ __launch_bounds__(256) void k_tangent_gate(
    const float* __restrict__ x, const float* __restrict__ Wg,
    const float* __restrict__ bg, __hip_bfloat16* __restrict__ xtb,
    float* __restrict__ gate, const float* __restrict__ Wp,
    __hip_bfloat16* __restrict__ Wt, int N) {
  int tb = (N + 3) >> 2;
  if ((int)blockIdx.x >= tb) {
    int idx = (blockIdx.x - tb) * 256 + threadIdx.x;
    if (idx < 512 * 128) {
      int n = idx >> 7, k = idx & 127;
      Wt[idx] = __float2bfloat16(Wp[(size_t)k * 512 + n]);
    }
    return;
  }
  int wid = (blockIdx.x * blockDim.x + threadIdx.x) >> 6;
  int lane = threadIdx.x & 63;
  if (wid >= N) return;

  const float* xr = x + (size_t)wid * 128;
  float2 xv = *(const float2*)(xr + lane * 2);
  xv.x = fminf(fmaxf(xv.x, -10000.f), 10000.f);
  xv.y = fminf(fmaxf(xv.y, -10000.f), 10000.f);

  float p = xv.x * xv.x + xv.y * xv.y;
  if (lane == 0) p -= 2.f * xv.x * xv.x;
  #pragma unroll
  for (int s = 32; s; s >>= 1) p += __shfl_xor(p, s);
  float x0 = __shfl(xv.x, 0);

  float denom = sqrtf(fmaxf(fabsf(p), 1e-12f));
  float cosd = fmaxf(x0 / denom, 1.0f + 1e-6f);
  float t = cosd - 1.0f;
  float coef = (t < 1e-3f)
      ? 1.0f - t * (1.f / 3.f) + t * t * (2.f / 15.f)
      : acoshf(cosd) * rsqrtf(t * (2.f + t));

  float2 o;
  o.x = coef * ((lane == 0) ? 2.0f * xv.x : xv.x);
  o.y = coef * xv.y;
  __hip_bfloat162 hb = __float22bfloat162_rn(make_float2(o.x, o.y));
  *(__hip_bfloat162*)(xtb + (size_t)wid * 128 + lane * 2) = hb;

  const float4 w0 = *(const float4*)(Wg + (size_t)(lane * 2) * 4);
  const float4 w1 = *(const float4*)(Wg + (size_t)(lane * 2 + 1) * 4);
  float g0 = o.x * w0.x + o.y * w1.x;
  float g1 = o.x * w0.y + o.y * w1.y;
  float g2 = o.x * w0.z + o.y * w1.z;
  float g3 = o.x * w0.w + o.y * w1.w;
  #pragma unroll
  for (int s = 32; s; s >>= 1) {
    g0 += __shfl_xor(g0, s); g1 += __shfl_xor(g1, s);
    g2 += __shfl_xor(g2, s); g3 += __shfl_xor(g3, s);
  }
  g0 += bg[0]; g1 += bg[1]; g2 += bg[2]; g3 += bg[3];
  float m = fmaxf(fmaxf(g0, g1), fmaxf(g2, g3));
  float e0 = expf(g0 - m), e1 = expf(g1 - m), e2 = expf(g2 - m), e3 = expf(g3 - m);
  float z = e0 + e1 + e2 + e3;
  if (lane == 0)
    *(float4*)(gate + (size_t)wid * 4) = make_float4(e0 / z, e1 / z, e2 / z, e3 / z);
}

// ---------------------------------------------------------------------------
// K2: u_hat via bf16 MFMA — B panel register-resident; all TPB tiles' A
// fragments prefetched up front (compile-time unrolled). Tail block range
// does the slot-scatter (consumer is k_route, which runs after).
// ---------------------------------------------------------------------------
#define TPB 4
__global__ __launch_bounds__(256, 2) void k_uhat_mfma(
    const short* __restrict__ xtb, const float* __restrict__ gate,
    const short* __restrict__ Wt, const float* __restrict__ bp,
    __half* __restrict__ uh, const int* __restrict__ row,
    const int* __restrict__ col, int* __restrict__ cnt,
    int* __restrict__ slots, int* __restrict__ ovf_cnt,
    int2* __restrict__ ovf, int N, int ntiles, int E) {
  int ub = (ntiles + TPB - 1) / TPB;
  if ((int)blockIdx.x >= ub) {
    // slot-scatter range: 2 edges per thread
    int e0 = ((blockIdx.x - ub) * 256 + threadIdx.x) * 2;
    #pragma unroll
    for (int k = 0; k < 2; ++k) {
      int e = e0 + k;
      if (e < E) {
        int c = col[e];
        int p = atomicAdd(&cnt[c], 1);
        if (p < CAP) slots[(size_t)c * CAP + p] = row[e];
        else { int q = atomicAdd(ovf_cnt, 1); ovf[q] = make_int2(c, row[e]); }
      }
    }
    return;
  }

  int lane = threadIdx.x & 63;
  int wv = threadIdx.x >> 6;
  int ri = lane & 15, kg = lane >> 4;
  int c_lo = wv * 32;

  // ---- preload B fragments + bias for this wave's 32 cols ----
  bf16x8 bfr[4][2][4];
  float bpv[4][2];
  #pragma unroll
  for (int p = 0; p < 4; ++p)
    #pragma unroll
    for (int n2 = 0; n2 < 2; ++n2) {
      int bcol = p * 128 + c_lo + n2 * 16 + ri;
      #pragma unroll
      for (int ks = 0; ks < 4; ++ks)
        bfr[p][n2][ks] = *(const bf16x8*)(Wt + (((size_t)bcol) << 7) + ks * 32 + kg * 8);
      bpv[p][n2] = bp[bcol];
    }

  int t0 = blockIdx.x * TPB;

  // ---- prefetch ALL TPB tiles' A fragments (issue back-to-back) ----
  bf16x8 af[TPB][4];
  #pragma unroll
  for (int tt = 0; tt < TPB; ++tt) {
    int t = t0 + tt;
    int r0 = t * 16 + ri;
    int c0 = (t < ntiles) ? ((r0 < N) ? r0 : (N - 1)) : 0;
    #pragma unroll
    for (int ks = 0; ks < 4; ++ks)
      af[tt][ks] = *(const bf16x8*)(xtb + (((size_t)c0) << 7) + ks * 32 + kg * 8);
  }

  #pragma unroll
  for (int tt = 0; tt < TPB; ++tt) {
    int t = t0 + tt;
    if (t < ntiles) {
      int m0 = t * 16;
      int rb = m0 + kg * 4;
      float gg[4][4];
      #pragma unroll
      for (int q = 0; q < 4; ++q) {
        int rm = rb + q;
        bool ok = rm < N;
        float4 gv = *(const float4*)(gate + (size_t)(ok ? rm : 0) * 4);
        gg[q][0] = ok ? gv.x : 0.f;
        gg[q][1] = ok ? gv.y : 0.f;
        gg[q][2] = ok ? gv.z : 0.f;
        gg[q][3] = ok ? gv.w : 0.f;
      }

      float fin[2][4];
      #pragma unroll
      for (int n2 = 0; n2 < 2; ++n2)
        #pragma unroll
        for (int q = 0; q < 4; ++q) fin[n2][q] = 0.f;

      #pragma unroll
      for (int p = 0; p < 4; ++p)
        #pragma unroll
        for (int n2 = 0; n2 < 2; ++n2) {
          f32x4 acc = {0.f, 0.f, 0.f, 0.f};
          #pragma unroll
          for (int ks = 0; ks < 4; ++ks)
            acc = __builtin_amdgcn_mfma_f32_16x16x32_bf16(af[tt][ks], bfr[p][n2][ks], acc, 0, 0, 0);
          #pragma unroll
          for (int q = 0; q < 4; ++q)
            fin[n2][q] += gg[q][p] * (acc[q] + bpv[p][n2]);
        }

      #pragma unroll
      for (int n2 = 0; n2 < 2; ++n2) {
        int cn = c_lo + n2 * 16 + ri;
        #pragma unroll
        for (int q = 0; q < 4; ++q) {
          int rm = rb + q;
          if (rm < N) uh[(size_t)rm * 128 + cn] = __float2half_rn(fin[n2][q]);
        }
      }
    }
  }
}

// ---------------------------------------------------------------------------
// K6: fused 3-iteration routing + squash + exp_map. (r16's proven kernel,
// unchanged: 1 wave/node, 64-thread blocks, separate gather/consume loops.)
// ---------------------------------------------------------------------------
__global__ __launch_bounds__(64, 4) void k_route(
    const __half* __restrict__ uh, const float* __restrict__ bias,
    const int* __restrict__ cnt, const int* __restrict__ slots,
    const int* __restrict__ ovf_cnt, const int2* __restrict__ ovf,
    int* __restrict__ fbc, int* __restrict__ claim,
    int* __restrict__ fb_rows, float* __restrict__ fb_b,
    float* __restrict__ out, int N) {
  __shared__ __align__(16) uint ssw[64];  // s as half2 words
  int lane = threadIdx.x;
  int j = blockIdx.x;
  int deg = cnt[j];
  int d0 = lane * 2;

  if (deg == 0) {
    *(float2*)(out + (size_t)j * 128 + d0) =
        make_float2((lane == 0) ? 1.f : 0.f, 0.f);
    return;
  }

  float2 bia = *(const float2*)(bias + d0);
  float s0 = 0.f, s1 = 0.f;

  if (deg <= CAP) {
    const uint* uhw = (const uint*)uh;
    int myrow = (lane < deg) ? slots[(size_t)j * CAP + lane] : 0;

    int e = lane >> 1, h = lane & 1;
    // dot-layout gather: lane-pair (e,h) loads edge e's half-row
    int er = __shfl(myrow, (e < deg) ? e : 0);
    const uint4* up = (const uint4*)(uhw + (((size_t)(uint)er) << 6) + h * 32);
    uint4 ud[8];
    #pragma unroll
    for (int k4 = 0; k4 < 8; ++k4) ud[k4] = up[k4];

    // dim-layout gather: chunked by 8, loads only (issue back-to-back)
    uint g[CAP];
    #pragma unroll
    for (int c = 0; c < CAP; c += 8) {
      if (c < deg) {   // wave-uniform branch
        #pragma unroll
        for (int k = 0; k < 8; ++k) {
          int i = c + k;
          int rr = __builtin_amdgcn_readlane(myrow, i);
          uint v = uhw[(((size_t)(uint)rr) << 6) + lane];
          g[i] = (i < deg) ? v : 0u;
        }
      }
    }

    // round-0 sum (c = 1/deg exactly) — separate consumption loop
    float a0 = 0.f, a1 = 0.f;
    #pragma unroll
    for (int c = 0; c < CAP; c += 8) {
      if (c < deg) {
        #pragma unroll
        for (int k = 0; k < 8; ++k) {
          int i = c + k;
          float2 uf = __half22float2(*(const __half2*)&g[i]);
          a0 += uf.x; a1 += uf.y;
        }
      }
    }

    float invd = 1.f / (float)deg;
    s0 = a0 * invd + bia.x;
    s1 = a1 * invd + bia.y;
    {
      float ns = s0 * s0 + s1 * s1;
      #pragma unroll
      for (int s = 32; s; s >>= 1) ns += __shfl_xor(ns, s);
      float scale = (ns / (1.f + ns)) * rsqrtf(ns + 1e-9f);
      s0 *= scale; s1 *= scale;
    }

    const uint* ssw_h = &ssw[h * 32];
    bool act = (e < deg);
    float b = 0.f;

    #pragma unroll
    for (int r = 0; r < 2; ++r) {
      // publish s (f16)
      __half2 sh2 = __floats2half2_rn(s0, s1);
      ssw[lane] = *(const uint*)&sh2;
      LGKM_FENCE();

      // per-edge dot from registers: 8 b128 s-reads + 32 fdot2
      float acc0 = 0.f, acc1 = 0.f;
      #pragma unroll
      for (int k4 = 0; k4 < 8; ++k4) {
        uint4 sw = *(const uint4*)&ssw_h[k4 * 4];
        acc0 = dot2acc(ud[k4].x, sw.x, acc0);
        acc1 = dot2acc(ud[k4].y, sw.y, acc1);
        acc0 = dot2acc(ud[k4].z, sw.z, acc0);
        acc1 = dot2acc(ud[k4].w, sw.w, acc1);
      }
      float acc = acc0 + acc1;
      acc += __shfl_xor(acc, 1);
      b += acc;
      float eb = act ? __expf(b) : 0.f;

      // weighted sum: chunked readlane, dual accumulators
      float z0 = 0.f, z1 = 0.f, wa0 = 0.f, wa1 = 0.f, wb0 = 0.f, wb1 = 0.f;
      #pragma unroll
      for (int c = 0; c < CAP; c += 8) {
        if (c < deg) {
          #pragma unroll
          for (int k = 0; k < 8; ++k) {
            int i = c + k;
            float ev = __uint_as_float(
                __builtin_amdgcn_readlane(__float_as_uint(eb), 2 * i));
            float2 uf = __half22float2(*(const __half2*)&g[i]);
            if (k & 1) { z1 += ev; wa1 = fmaf(ev, uf.x, wa1); wb1 = fmaf(ev, uf.y, wb1); }
            else       { z0 += ev; wa0 = fmaf(ev, uf.x, wa0); wb0 = fmaf(ev, uf.y, wb0); }
          }
        }
      }
      float z = z0 + z1;
      float invz = 1.f / z;
      s0 = (wa0 + wa1) * invz + bia.x;
      s1 = (wb0 + wb1) * invz + bia.y;
      float ns = s0 * s0 + s1 * s1;
      #pragma unroll
      for (int s = 32; s; s >>= 1) ns += __shfl_xor(ns, s);
      float scale = (ns / (1.f + ns)) * rsqrtf(ns + 1e-9f);
      s0 *= scale; s1 *= scale;
    }
  } else {
    // fallback (deg > CAP, ~never): collect rows from slots + overflow list
    int base = 0;
    if (lane == 0) base = atomicAdd(claim, deg);
    base = __shfl(base, 0);
    int* mr = fb_rows + base;
    float* b = fb_b + base;
    if (lane < CAP) mr[lane] = slots[(size_t)j * CAP + lane];
    int novf = *ovf_cnt;
    for (int t = lane; t < novf; t += 64) {
      int2 ov = ovf[t];
      if (ov.x == j) {
        int p = atomicAdd(&fbc[j], 1);
        mr[CAP + p] = ov.y;
      }
    }
    asm volatile("s_waitcnt vmcnt(0)" ::: "memory");

    const __half2* uh2 = (const __half2*)uh;
    for (int i = lane; i < deg; i += 64) atomicExch(&b[i], 0.f);
    asm volatile("s_waitcnt vmcnt(0)" ::: "memory");

    for (int r = 0; r < 3; ++r) {
      float mx = -3.4e38f;
      for (int i = lane; i < deg; i += 64)
        mx = fmaxf(mx, atomicAdd(&b[i], 0.f));
      #pragma unroll
      for (int s = 32; s; s >>= 1) mx = fmaxf(mx, __shfl_xor(mx, s));
      float z = 0.f;
      for (int i = lane; i < deg; i += 64) z += expf(atomicAdd(&b[i], 0.f) - mx);
      #pragma unroll
      for (int s = 32; s; s >>= 1) z += __shfl_xor(z, s);
      float invz = 1.f / z;

      s0 = 0.f; s1 = 0.f;
      for (int i = 0; i < deg; ++i) {
        float c = expf(atomicAdd(&b[i], 0.f) - mx) * invz;
        int rr = mr[i];
        float2 uf = __half22float2(uh2[(((size_t)rr) << 6) + lane]);
        s0 = fmaf(c, uf.x, s0);
        s1 = fmaf(c, uf.y, s1);
      }
      s0 += bia.x; s1 += bia.y;

      float ns = s0 * s0 + s1 * s1;
      #pragma unroll
      for (int s = 32; s; s >>= 1) ns += __shfl_xor(ns, s);
      float scale = (ns / (1.f + ns)) * rsqrtf(ns + 1e-9f);
      s0 *= scale; s1 *= scale;

      if (r < 2) {
        for (int i = 0; i < deg; ++i) {
          int rr = mr[i];
          float2 uf = __half22float2(uh2[(((size_t)rr) << 6) + lane]);
          float pp = s0 * uf.x + s1 * uf.y;
          #pragma unroll
          for (int s = 32; s; s >>= 1) pp += __shfl_xor(pp, s);
          if (lane == 0) atomicAdd(&b[i], pp);
        }
        asm volatile("s_waitcnt vmcnt(0)" ::: "memory");
      }
    }
  }

  // exp_map(s, ref)
  float pn = s0 * s0 + s1 * s1;
  if (lane == 0) pn -= 2.f * s0 * s0;
  #pragma unroll
  for (int s = 32; s; s >>= 1) pn += __shfl_xor(pn, s);
  float vn = fminf(sqrtf(fabsf(pn) + 1e-12f), 10.f);
  float sh = sinhf(vn) / vn;
  float ov0 = sh * s0 + ((lane == 0) ? coshf(vn) : 0.f);
  float ov1 = sh * s1;
  *(float2*)(out + (size_t)j * 128 + d0) = make_float2(ov0, ov1);
}

// ---------------------------------------------------------------------------
extern "C" void kernel_launch(void* const* d_in, const int* in_sizes, int n_in,
                              void* d_out, int out_size, void* d_ws, size_t ws_size,
                              hipStream_t stream) {
  const float* x    = (const float*)d_in[0];
  const int*   ei   = (const int*)d_in[1];
  const float* Wp   = (const float*)d_in[2];
  const float* bp   = (const float*)d_in[3];
  const float* Wg   = (const float*)d_in[4];
  const float* bg   = (const float*)d_in[5];
  const float* bias = (const float*)d_in[6];
  float* out = (float*)d_out;

  int N = in_sizes[0] / 128;
  int E = in_sizes[1] / 2;
  const int* row = ei;
  const int* col = ei + E;

  __hip_bfloat16* xtb = (__hip_bfloat16*)d_ws;                  // N*128 bf16
  __half* uhh = (__half*)(xtb + (size_t)N * 128);               // N*128 f16
  float* gate = (float*)(uhh + (size_t)N * 128);                // N*4 f32
  __hip_bfloat16* Wt = (__hip_bfloat16*)(gate + (size_t)N * 4); // 512*128 bf16
  int* cnt = (int*)(Wt + 512 * 128);                            // N
  int* fbc = cnt + N;                                           // N
  int* claim = fbc + N;                                         // 1
  int* ovf_cnt = claim + 1;                                     // 1
  int* slots = ovf_cnt + 1;                                     // N*CAP
  int2* ovf = (int2*)(slots + (size_t)N * CAP);                 // E int2
  int* fb_rows = (int*)(ovf + E);                               // E
  float* fb_b = (float*)(fb_rows + E);                          // E

  int tb = (N + 3) / 4;
  int hb = (E + 511) / 512;
  int ntiles = (N + 15) / 16;
  int ub = (ntiles + TPB - 1) / TPB;
  (void)hipMemsetAsync(cnt, 0, ((size_t)2 * N + 2) * sizeof(int), stream);
  k_tangent_gate<<<tb + 256, 256, 0, stream>>>(x, Wg, bg, xtb, gate, Wp, Wt, N);
  k_uhat_mfma<<<ub + hb, 256, 0, stream>>>(
      (const short*)xtb, gate, (const short*)Wt, bp, uhh,
      row, col, cnt, slots, ovf_cnt, ovf, N, ntiles, E);
  k_route<<<N, 64, 0, stream>>>(
      uhh, bias, cnt, slots, ovf_cnt, ovf, fbc, claim, fb_rows, fb_b, out, N);
}

// Round 18
// 138.682 us; speedup vs baseline: 1.1683x; 1.0996x over previous
//
#include <hip/hip_runtime.h>
#include <hip/hip_fp16.h>
#include <hip/hip_bf16.h>

typedef short bf16x8 __attribute__((ext_vector_type(8)));
typedef float f32x4 __attribute__((ext_vector_type(4)));
typedef _Float16 f16x2 __attribute__((ext_vector_type(2)));

#define LGKM_FENCE() asm volatile("s_waitcnt lgkmcnt(0)" ::: "memory")
#define CAP 32

static __device__ __forceinline__ f16x2 as_f16x2(uint v) {
  union { uint u; f16x2 h; } c; c.u = v; return c.h;
}

static __device__ __forceinline__ float dot2acc(uint a, uint b, float c) {
#if __has_builtin(__builtin_amdgcn_fdot2)
  return __builtin_amdgcn_fdot2(as_f16x2(a), as_f16x2(b), c, false);
#else
  float2 af = __half22float2(*(const __half2*)&a);
  float2 bf = __half22float2(*(const __half2*)&b);
  return fmaf(af.x, bf.x, fmaf(af.y, bf.y, c));
#endif
}

// ---------------------------------------------------------------------------
// K1: per-node log_map (bf16 out) + gate softmax; tail range: W transpose.
// ---------------------------------------------------------------------------
__global__ __launch_bounds__(256) void k_tangent_gate(
    const float* __restrict__ x, const float* __restrict__ Wg,
    const float* __restrict__ bg, __hip_bfloat16* __restrict__ xtb,
    float* __restrict__ gate, const float* __restrict__ Wp,
    __hip_bfloat16* __restrict__ Wt, int N) {
  int tb = (N + 3) >> 2;
  if ((int)blockIdx.x >= tb) {
    int idx = (blockIdx.x - tb) * 256 + threadIdx.x;
    if (idx < 512 * 128) {
      int n = idx >> 7, k = idx & 127;
      Wt[idx] = __float2bfloat16(Wp[(size_t)k * 512 + n]);
    }
    return;
  }
  int wid = (blockIdx.x * blockDim.x + threadIdx.x) >> 6;
  int lane = threadIdx.x & 63;
  if (wid >= N) return;

  const float* xr = x + (size_t)wid * 128;
  float2 xv = *(const float2*)(xr + lane * 2);
  xv.x = fminf(fmaxf(xv.x, -10000.f), 10000.f);
  xv.y = fminf(fmaxf(xv.y, -10000.f), 10000.f);

  float p = xv.x * xv.x + xv.y * xv.y;
  if (lane == 0) p -= 2.f * xv.x * xv.x;
  #pragma unroll
  for (int s = 32; s; s >>= 1) p += __shfl_xor(p, s);
  float x0 = __shfl(xv.x, 0);

  float denom = sqrtf(fmaxf(fabsf(p), 1e-12f));
  float cosd = fmaxf(x0 / denom, 1.0f + 1e-6f);
  float t = cosd - 1.0f;
  float coef = (t < 1e-3f)
      ? 1.0f - t * (1.f / 3.f) + t * t * (2.f / 15.f)
      : acoshf(cosd) * rsqrtf(t * (2.f + t));

  float2 o;
  o.x = coef * ((lane == 0) ? 2.0f * xv.x : xv.x);
  o.y = coef * xv.y;
  __hip_bfloat162 hb = __float22bfloat162_rn(make_float2(o.x, o.y));
  *(__hip_bfloat162*)(xtb + (size_t)wid * 128 + lane * 2) = hb;

  const float4 w0 = *(const float4*)(Wg + (size_t)(lane * 2) * 4);
  const float4 w1 = *(const float4*)(Wg + (size_t)(lane * 2 + 1) * 4);
  float g0 = o.x * w0.x + o.y * w1.x;
  float g1 = o.x * w0.y + o.y * w1.y;
  float g2 = o.x * w0.z + o.y * w1.z;
  float g3 = o.x * w0.w + o.y * w1.w;
  #pragma unroll
  for (int s = 32; s; s >>= 1) {
    g0 += __shfl_xor(g0, s); g1 += __shfl_xor(g1, s);
    g2 += __shfl_xor(g2, s); g3 += __shfl_xor(g3, s);
  }
  g0 += bg[0]; g1 += bg[1]; g2 += bg[2]; g3 += bg[3];
  float m = fmaxf(fmaxf(g0, g1), fmaxf(g2, g3));
  float e0 = expf(g0 - m), e1 = expf(g1 - m), e2 = expf(g2 - m), e3 = expf(g3 - m);
  float z = e0 + e1 + e2 + e3;
  if (lane == 0)
    *(float4*)(gate + (size_t)wid * 4) = make_float4(e0 / z, e1 / z, e2 / z, e3 / z);
}

// ---------------------------------------------------------------------------
// K2: u_hat via bf16 MFMA — B panel register-resident; TPB tiles' A frags
// prefetched; tail block range does the slot-scatter.
// ---------------------------------------------------------------------------
#define TPB 4
__global__ __launch_bounds__(256, 2) void k_uhat_mfma(
    const short* __restrict__ xtb, const float* __restrict__ gate,
    const short* __restrict__ Wt, const float* __restrict__ bp,
    __half* __restrict__ uh, const int* __restrict__ row,
    const int* __restrict__ col, int* __restrict__ cnt,
    int* __restrict__ slots, int* __restrict__ ovf_cnt,
    int2* __restrict__ ovf, int N, int ntiles, int E) {
  int ub = (ntiles + TPB - 1) / TPB;
  if ((int)blockIdx.x >= ub) {
    int e0 = ((blockIdx.x - ub) * 256 + threadIdx.x) * 2;
    #pragma unroll
    for (int k = 0; k < 2; ++k) {
      int e = e0 + k;
      if (e < E) {
        int c = col[e];
        int p = atomicAdd(&cnt[c], 1);
        if (p < CAP) slots[(size_t)c * CAP + p] = row[e];
        else { int q = atomicAdd(ovf_cnt, 1); ovf[q] = make_int2(c, row[e]); }
      }
    }
    return;
  }

  int lane = threadIdx.x & 63;
  int wv = threadIdx.x >> 6;
  int ri = lane & 15, kg = lane >> 4;
  int c_lo = wv * 32;

  bf16x8 bfr[4][2][4];
  float bpv[4][2];
  #pragma unroll
  for (int p = 0; p < 4; ++p)
    #pragma unroll
    for (int n2 = 0; n2 < 2; ++n2) {
      int bcol = p * 128 + c_lo + n2 * 16 + ri;
      #pragma unroll
      for (int ks = 0; ks < 4; ++ks)
        bfr[p][n2][ks] = *(const bf16x8*)(Wt + (((size_t)bcol) << 7) + ks * 32 + kg * 8);
      bpv[p][n2] = bp[bcol];
    }

  int t0 = blockIdx.x * TPB;

  bf16x8 af[TPB][4];
  #pragma unroll
  for (int tt = 0; tt < TPB; ++tt) {
    int t = t0 + tt;
    int r0 = t * 16 + ri;
    int c0 = (t < ntiles) ? ((r0 < N) ? r0 : (N - 1)) : 0;
    #pragma unroll
    for (int ks = 0; ks < 4; ++ks)
      af[tt][ks] = *(const bf16x8*)(xtb + (((size_t)c0) << 7) + ks * 32 + kg * 8);
  }

  #pragma unroll
  for (int tt = 0; tt < TPB; ++tt) {
    int t = t0 + tt;
    if (t < ntiles) {
      int m0 = t * 16;
      int rb = m0 + kg * 4;
      float gg[4][4];
      #pragma unroll
      for (int q = 0; q < 4; ++q) {
        int rm = rb + q;
        bool ok = rm < N;
        float4 gv = *(const float4*)(gate + (size_t)(ok ? rm : 0) * 4);
        gg[q][0] = ok ? gv.x : 0.f;
        gg[q][1] = ok ? gv.y : 0.f;
        gg[q][2] = ok ? gv.z : 0.f;
        gg[q][3] = ok ? gv.w : 0.f;
      }

      float fin[2][4];
      #pragma unroll
      for (int n2 = 0; n2 < 2; ++n2)
        #pragma unroll
        for (int q = 0; q < 4; ++q) fin[n2][q] = 0.f;

      #pragma unroll
      for (int p = 0; p < 4; ++p)
        #pragma unroll
        for (int n2 = 0; n2 < 2; ++n2) {
          f32x4 acc = {0.f, 0.f, 0.f, 0.f};
          #pragma unroll
          for (int ks = 0; ks < 4; ++ks)
            acc = __builtin_amdgcn_mfma_f32_16x16x32_bf16(af[tt][ks], bfr[p][n2][ks], acc, 0, 0, 0);
          #pragma unroll
          for (int q = 0; q < 4; ++q)
            fin[n2][q] += gg[q][p] * (acc[q] + bpv[p][n2]);
        }

      #pragma unroll
      for (int n2 = 0; n2 < 2; ++n2) {
        int cn = c_lo + n2 * 16 + ri;
        #pragma unroll
        for (int q = 0; q < 4; ++q) {
          int rm = rb + q;
          if (rm < N) uh[(size_t)rm * 128 + cn] = __float2half_rn(fin[n2][q]);
        }
      }
    }
  }
}

// ---------------------------------------------------------------------------
// K6: fused 3-iteration routing + squash + exp_map. One wave per node.
// NEW deg<=16 fast path (92% of nodes): quarter-dot layout (e=lane>>2,
// q=lane&3) -> ud4[4], 16 fdot2 + 4 LDS reads/round (was 32+8); u
// pre-converted to f32 once (uf[16]) so ws loops skip cvt.
// deg 17..32: r16 path. deg>32: fallback. All selections wave-uniform.
// ---------------------------------------------------------------------------
__global__ __launch_bounds__(64, 4) void k_route(
    const __half* __restrict__ uh, const float* __restrict__ bias,
    const int* __restrict__ cnt, const int* __restrict__ slots,
    const int* __restrict__ ovf_cnt, const int2* __restrict__ ovf,
    int* __restrict__ fbc, int* __restrict__ claim,
    int* __restrict__ fb_rows, float* __restrict__ fb_b,
    float* __restrict__ out, int N) {
  __shared__ __align__(16) uint ssw[64];  // s as half2 words
  int lane = threadIdx.x;
  int j = blockIdx.x;
  int deg = cnt[j];
  int d0 = lane * 2;

  if (deg == 0) {
    *(float2*)(out + (size_t)j * 128 + d0) =
        make_float2((lane == 0) ? 1.f : 0.f, 0.f);
    return;
  }

  float2 bia = *(const float2*)(bias + d0);
  float s0 = 0.f, s1 = 0.f;
  const uint* uhw = (const uint*)uh;

  if (deg <= 16) {
    // ================= FAST PATH (deg <= 16) =================
    int myrow = (lane < deg) ? slots[(size_t)j * CAP + lane] : 0;

    int e = lane >> 2, q = lane & 3;
    // quarter-dot gather: 4 lanes per edge, each loads 16 words
    int er = __shfl(myrow, (e < deg) ? e : 0);
    const uint4* up = (const uint4*)(uhw + (((size_t)(uint)er) << 6) + q * 16);
    uint4 ud4[4];
    #pragma unroll
    for (int w4 = 0; w4 < 4; ++w4) ud4[w4] = up[w4];

    // dim-layout gather: chunked by 8, loads only
    uint g[16];
    #pragma unroll
    for (int c = 0; c < 16; c += 8) {
      if (c < deg) {
        #pragma unroll
        for (int k = 0; k < 8; ++k) {
          int i = c + k;
          int rr = __builtin_amdgcn_readlane(myrow, i);
          uint v = uhw[(((size_t)(uint)rr) << 6) + lane];
          g[i] = (i < deg) ? v : 0u;
        }
      }
    }

    // convert once + round-0 sum (c = 1/deg exactly)
    float2 uf[16];
    float a0 = 0.f, a1 = 0.f;
    #pragma unroll
    for (int c = 0; c < 16; c += 8) {
      if (c < deg) {
        #pragma unroll
        for (int k = 0; k < 8; ++k) {
          int i = c + k;
          uf[i] = __half22float2(*(const __half2*)&g[i]);
          a0 += uf[i].x; a1 += uf[i].y;
        }
      }
    }

    float invd = 1.f / (float)deg;
    s0 = a0 * invd + bia.x;
    s1 = a1 * invd + bia.y;
    {
      float ns = s0 * s0 + s1 * s1;
      #pragma unroll
      for (int s = 32; s; s >>= 1) ns += __shfl_xor(ns, s);
      float scale = (ns / (1.f + ns)) * rsqrtf(ns + 1e-9f);
      s0 *= scale; s1 *= scale;
    }

    const uint* ssw_q = &ssw[q * 16];
    bool act = (e < deg);
    float b = 0.f;

    #pragma unroll
    for (int r = 0; r < 2; ++r) {
      __half2 sh2 = __floats2half2_rn(s0, s1);
      ssw[lane] = *(const uint*)&sh2;
      LGKM_FENCE();

      // per-edge dot: 4 b128 s-reads + 16 fdot2, 4-lane reduce
      float acc0 = 0.f, acc1 = 0.f;
      #pragma unroll
      for (int w4 = 0; w4 < 4; ++w4) {
        uint4 sw = *(const uint4*)&ssw_q[w4 * 4];
        acc0 = dot2acc(ud4[w4].x, sw.x, acc0);
        acc1 = dot2acc(ud4[w4].y, sw.y, acc1);
        acc0 = dot2acc(ud4[w4].z, sw.z, acc0);
        acc1 = dot2acc(ud4[w4].w, sw.w, acc1);
      }
      float acc = acc0 + acc1;
      acc += __shfl_xor(acc, 1);
      acc += __shfl_xor(acc, 2);
      b += acc;
      float eb = act ? __expf(b) : 0.f;

      // weighted sum from pre-converted uf
      float z0 = 0.f, z1 = 0.f, wa0 = 0.f, wa1 = 0.f, wb0 = 0.f, wb1 = 0.f;
      #pragma unroll
      for (int c = 0; c < 16; c += 8) {
        if (c < deg) {
          #pragma unroll
          for (int k = 0; k < 8; ++k) {
            int i = c + k;
            float ev = __uint_as_float(
                __builtin_amdgcn_readlane(__float_as_uint(eb), 4 * i));
            if (k & 1) { z1 += ev; wa1 = fmaf(ev, uf[i].x, wa1); wb1 = fmaf(ev, uf[i].y, wb1); }
            else       { z0 += ev; wa0 = fmaf(ev, uf[i].x, wa0); wb0 = fmaf(ev, uf[i].y, wb0); }
          }
        }
      }
      float z = z0 + z1;
      float invz = 1.f / z;
      s0 = (wa0 + wa1) * invz + bia.x;
      s1 = (wb0 + wb1) * invz + bia.y;
      float ns = s0 * s0 + s1 * s1;
      #pragma unroll
      for (int s = 32; s; s >>= 1) ns += __shfl_xor(ns, s);
      float scale = (ns / (1.f + ns)) * rsqrtf(ns + 1e-9f);
      s0 *= scale; s1 *= scale;
    }
  } else if (deg <= CAP) {
    // ================= MEDIUM PATH (17..32) — r16 verbatim =================
    int myrow = (lane < deg) ? slots[(size_t)j * CAP + lane] : 0;

    int e = lane >> 1, h = lane & 1;
    int er = __shfl(myrow, (e < deg) ? e : 0);
    const uint4* up = (const uint4*)(uhw + (((size_t)(uint)er) << 6) + h * 32);
    uint4 ud[8];
    #pragma unroll
    for (int k4 = 0; k4 < 8; ++k4) ud[k4] = up[k4];

    uint g[CAP];
    #pragma unroll
    for (int c = 0; c < CAP; c += 8) {
      if (c < deg) {
        #pragma unroll
        for (int k = 0; k < 8; ++k) {
          int i = c + k;
          int rr = __builtin_amdgcn_readlane(myrow, i);
          uint v = uhw[(((size_t)(uint)rr) << 6) + lane];
          g[i] = (i < deg) ? v : 0u;
        }
      }
    }

    float a0 = 0.f, a1 = 0.f;
    #pragma unroll
    for (int c = 0; c < CAP; c += 8) {
      if (c < deg) {
        #pragma unroll
        for (int k = 0; k < 8; ++k) {
          int i = c + k;
          float2 uf = __half22float2(*(const __half2*)&g[i]);
          a0 += uf.x; a1 += uf.y;
        }
      }
    }

    float invd = 1.f / (float)deg;
    s0 = a0 * invd + bia.x;
    s1 = a1 * invd + bia.y;
    {
      float ns = s0 * s0 + s1 * s1;
      #pragma unroll
      for (int s = 32; s; s >>= 1) ns += __shfl_xor(ns, s);
      float scale = (ns / (1.f + ns)) * rsqrtf(ns + 1e-9f);
      s0 *= scale; s1 *= scale;
    }

    const uint* ssw_h = &ssw[h * 32];
    bool act = (e < deg);
    float b = 0.f;

    #pragma unroll
    for (int r = 0; r < 2; ++r) {
      __half2 sh2 = __floats2half2_rn(s0, s1);
      ssw[lane] = *(const uint*)&sh2;
      LGKM_FENCE();

      float acc0 = 0.f, acc1 = 0.f;
      #pragma unroll
      for (int k4 = 0; k4 < 8; ++k4) {
        uint4 sw = *(const uint4*)&ssw_h[k4 * 4];
        acc0 = dot2acc(ud[k4].x, sw.x, acc0);
        acc1 = dot2acc(ud[k4].y, sw.y, acc1);
        acc0 = dot2acc(ud[k4].z, sw.z, acc0);
        acc1 = dot2acc(ud[k4].w, sw.w, acc1);
      }
      float acc = acc0 + acc1;
      acc += __shfl_xor(acc, 1);
      b += acc;
      float eb = act ? __expf(b) : 0.f;

      float z0 = 0.f, z1 = 0.f, wa0 = 0.f, wa1 = 0.f, wb0 = 0.f, wb1 = 0.f;
      #pragma unroll
      for (int c = 0; c < CAP; c += 8) {
        if (c < deg) {
          #pragma unroll
          for (int k = 0; k < 8; ++k) {
            int i = c + k;
            float ev = __uint_as_float(
                __builtin_amdgcn_readlane(__float_as_uint(eb), 2 * i));
            float2 uf = __half22float2(*(const __half2*)&g[i]);
            if (k & 1) { z1 += ev; wa1 = fmaf(ev, uf.x, wa1); wb1 = fmaf(ev, uf.y, wb1); }
            else       { z0 += ev; wa0 = fmaf(ev, uf.x, wa0); wb0 = fmaf(ev, uf.y, wb0); }
          }
        }
      }
      float z = z0 + z1;
      float invz = 1.f / z;
      s0 = (wa0 + wa1) * invz + bia.x;
      s1 = (wb0 + wb1) * invz + bia.y;
      float ns = s0 * s0 + s1 * s1;
      #pragma unroll
      for (int s = 32; s; s >>= 1) ns += __shfl_xor(ns, s);
      float scale = (ns / (1.f + ns)) * rsqrtf(ns + 1e-9f);
      s0 *= scale; s1 *= scale;
    }
  } else {
    // ================= FALLBACK (deg > 32, ~never) =================
    int base = 0;
    if (lane == 0) base = atomicAdd(claim, deg);
    base = __shfl(base, 0);
    int* mr = fb_rows + base;
    float* b = fb_b + base;
    if (lane < CAP) mr[lane] = slots[(size_t)j * CAP + lane];
    int novf = *ovf_cnt;
    for (int t = lane; t < novf; t += 64) {
      int2 ov = ovf[t];
      if (ov.x == j) {
        int p = atomicAdd(&fbc[j], 1);
        mr[CAP + p] = ov.y;
      }
    }
    asm volatile("s_waitcnt vmcnt(0)" ::: "memory");

    const __half2* uh2 = (const __half2*)uh;
    for (int i = lane; i < deg; i += 64) atomicExch(&b[i], 0.f);
    asm volatile("s_waitcnt vmcnt(0)" ::: "memory");

    for (int r = 0; r < 3; ++r) {
      float mx = -3.4e38f;
      for (int i = lane; i < deg; i += 64)
        mx = fmaxf(mx, atomicAdd(&b[i], 0.f));
      #pragma unroll
      for (int s = 32; s; s >>= 1) mx = fmaxf(mx, __shfl_xor(mx, s));
      float z = 0.f;
      for (int i = lane; i < deg; i += 64) z += expf(atomicAdd(&b[i], 0.f) - mx);
      #pragma unroll
      for (int s = 32; s; s >>= 1) z += __shfl_xor(z, s);
      float invz = 1.f / z;

      s0 = 0.f; s1 = 0.f;
      for (int i = 0; i < deg; ++i) {
        float c = expf(atomicAdd(&b[i], 0.f) - mx) * invz;
        int rr = mr[i];
        float2 uf = __half22float2(uh2[(((size_t)rr) << 6) + lane]);
        s0 = fmaf(c, uf.x, s0);
        s1 = fmaf(c, uf.y, s1);
      }
      s0 += bia.x; s1 += bia.y;

      float ns = s0 * s0 + s1 * s1;
      #pragma unroll
      for (int s = 32; s; s >>= 1) ns += __shfl_xor(ns, s);
      float scale = (ns / (1.f + ns)) * rsqrtf(ns + 1e-9f);
      s0 *= scale; s1 *= scale;

      if (r < 2) {
        for (int i = 0; i < deg; ++i) {
          int rr = mr[i];
          float2 uf = __half22float2(uh2[(((size_t)rr) << 6) + lane]);
          float pp = s0 * uf.x + s1 * uf.y;
          #pragma unroll
          for (int s = 32; s; s >>= 1) pp += __shfl_xor(pp, s);
          if (lane == 0) atomicAdd(&b[i], pp);
        }
        asm volatile("s_waitcnt vmcnt(0)" ::: "memory");
      }
    }
  }

  // exp_map(s, ref)
  float pn = s0 * s0 + s1 * s1;
  if (lane == 0) pn -= 2.f * s0 * s0;
  #pragma unroll
  for (int s = 32; s; s >>= 1) pn += __shfl_xor(pn, s);
  float vn = fminf(sqrtf(fabsf(pn) + 1e-12f), 10.f);
  float sh = sinhf(vn) / vn;
  float ov0 = sh * s0 + ((lane == 0) ? coshf(vn) : 0.f);
  float ov1 = sh * s1;
  *(float2*)(out + (size_t)j * 128 + d0) = make_float2(ov0, ov1);
}

// ---------------------------------------------------------------------------
extern "C" void kernel_launch(void* const* d_in, const int* in_sizes, int n_in,
                              void* d_out, int out_size, void* d_ws, size_t ws_size,
                              hipStream_t stream) {
  const float* x    = (const float*)d_in[0];
  const int*   ei   = (const int*)d_in[1];
  const float* Wp   = (const float*)d_in[2];
  const float* bp   = (const float*)d_in[3];
  const float* Wg   = (const float*)d_in[4];
  const float* bg   = (const float*)d_in[5];
  const float* bias = (const float*)d_in[6];
  float* out = (float*)d_out;

  int N = in_sizes[0] / 128;
  int E = in_sizes[1] / 2;
  const int* row = ei;
  const int* col = ei + E;

  __hip_bfloat16* xtb = (__hip_bfloat16*)d_ws;                  // N*128 bf16
  __half* uhh = (__half*)(xtb + (size_t)N * 128);               // N*128 f16
  float* gate = (float*)(uhh + (size_t)N * 128);                // N*4 f32
  __hip_bfloat16* Wt = (__hip_bfloat16*)(gate + (size_t)N * 4); // 512*128 bf16
  int* cnt = (int*)(Wt + 512 * 128);                            // N
  int* fbc = cnt + N;                                           // N
  int* claim = fbc + N;                                         // 1
  int* ovf_cnt = claim + 1;                                     // 1
  int* slots = ovf_cnt + 1;                                     // N*CAP
  int2* ovf = (int2*)(slots + (size_t)N * CAP);                 // E int2
  int* fb_rows = (int*)(ovf + E);                               // E
  float* fb_b = (float*)(fb_rows + E);                          // E

  int tb = (N + 3) / 4;
  int hb = (E + 511) / 512;
  int ntiles = (N + 15) / 16;
  int ub = (ntiles + TPB - 1) / TPB;
  (void)hipMemsetAsync(cnt, 0, ((size_t)2 * N + 2) * sizeof(int), stream);
  k_tangent_gate<<<tb + 256, 256, 0, stream>>>(x, Wg, bg, xtb, gate, Wp, Wt, N);
  k_uhat_mfma<<<ub + hb, 256, 0, stream>>>(
      (const short*)xtb, gate, (const short*)Wt, bp, uhh,
      row, col, cnt, slots, ovf_cnt, ovf, N, ntiles, E);
  k_route<<<N, 64, 0, stream>>>(
      uhh, bias, cnt, slots, ovf_cnt, ovf, fbc, claim, fb_rows, fb_b, out, N);
}

// Round 19
// 125.929 us; speedup vs baseline: 1.2866x; 1.1013x over previous
//
#include <hip/hip_runtime.h>
#include <hip/hip_fp16.h>
#include <hip/hip_bf16.h>

typedef short bf16x8 __attribute__((ext_vector_type(8)));
typedef float f32x4 __attribute__((ext_vector_type(4)));
typedef _Float16 f16x2 __attribute__((ext_vector_type(2)));

#define LGKM_FENCE() asm volatile("s_waitcnt lgkmcnt(0)" ::: "memory")
#define CAP 32

static __device__ __forceinline__ f16x2 as_f16x2(uint v) {
  union { uint u; f16x2 h; } c; c.u = v; return c.h;
}

static __device__ __forceinline__ float dot2acc(uint a, uint b, float c) {
#if __has_builtin(__builtin_amdgcn_fdot2)
  return __builtin_amdgcn_fdot2(as_f16x2(a), as_f16x2(b), c, false);
#else
  float2 af = __half22float2(*(const __half2*)&a);
  float2 bf = __half22float2(*(const __half2*)&b);
  return fmaf(af.x, bf.x, fmaf(af.y, bf.y, c));
#endif
}

// ---------------------------------------------------------------------------
// K1: per-node log_map (bf16 out) + gate softmax; tail ranges: W transpose
// AND zero-init of cnt/fbc/claim/ovf_cnt (consumed first by k_uhat).
// ---------------------------------------------------------------------------
__global__ __launch_bounds__(256) void k_tangent_gate(
    const float* __restrict__ x, const float* __restrict__ Wg,
    const float* __restrict__ bg, __hip_bfloat16* __restrict__ xtb,
    float* __restrict__ gate, const float* __restrict__ Wp,
    __hip_bfloat16* __restrict__ Wt, int* __restrict__ zbase,
    int nz, int N) {
  int tb = (N + 3) >> 2;
  if ((int)blockIdx.x >= tb + 256) {
    // zero-init range
    int idx = (blockIdx.x - tb - 256) * 256 + threadIdx.x;
    if (idx < nz) zbase[idx] = 0;
    return;
  }
  if ((int)blockIdx.x >= tb) {
    int idx = (blockIdx.x - tb) * 256 + threadIdx.x;
    if (idx < 512 * 128) {
      int n = idx >> 7, k = idx & 127;
      Wt[idx] = __float2bfloat16(Wp[(size_t)k * 512 + n]);
    }
    return;
  }
  int wid = (blockIdx.x * blockDim.x + threadIdx.x) >> 6;
  int lane = threadIdx.x & 63;
  if (wid >= N) return;

  const float* xr = x + (size_t)wid * 128;
  float2 xv = *(const float2*)(xr + lane * 2);
  xv.x = fminf(fmaxf(xv.x, -10000.f), 10000.f);
  xv.y = fminf(fmaxf(xv.y, -10000.f), 10000.f);

  float p = xv.x * xv.x + xv.y * xv.y;
  if (lane == 0) p -= 2.f * xv.x * xv.x;
  #pragma unroll
  for (int s = 32; s; s >>= 1) p += __shfl_xor(p, s);
  float x0 = __shfl(xv.x, 0);

  float denom = sqrtf(fmaxf(fabsf(p), 1e-12f));
  float cosd = fmaxf(x0 / denom, 1.0f + 1e-6f);
  float t = cosd - 1.0f;
  float coef = (t < 1e-3f)
      ? 1.0f - t * (1.f / 3.f) + t * t * (2.f / 15.f)
      : acoshf(cosd) * rsqrtf(t * (2.f + t));

  float2 o;
  o.x = coef * ((lane == 0) ? 2.0f * xv.x : xv.x);
  o.y = coef * xv.y;
  __hip_bfloat162 hb = __float22bfloat162_rn(make_float2(o.x, o.y));
  *(__hip_bfloat162*)(xtb + (size_t)wid * 128 + lane * 2) = hb;

  const float4 w0 = *(const float4*)(Wg + (size_t)(lane * 2) * 4);
  const float4 w1 = *(const float4*)(Wg + (size_t)(lane * 2 + 1) * 4);
  float g0 = o.x * w0.x + o.y * w1.x;
  float g1 = o.x * w0.y + o.y * w1.y;
  float g2 = o.x * w0.z + o.y * w1.z;
  float g3 = o.x * w0.w + o.y * w1.w;
  #pragma unroll
  for (int s = 32; s; s >>= 1) {
    g0 += __shfl_xor(g0, s); g1 += __shfl_xor(g1, s);
    g2 += __shfl_xor(g2, s); g3 += __shfl_xor(g3, s);
  }
  g0 += bg[0]; g1 += bg[1]; g2 += bg[2]; g3 += bg[3];
  float m = fmaxf(fmaxf(g0, g1), fmaxf(g2, g3));
  float e0 = expf(g0 - m), e1 = expf(g1 - m), e2 = expf(g2 - m), e3 = expf(g3 - m);
  float z = e0 + e1 + e2 + e3;
  if (lane == 0)
    *(float4*)(gate + (size_t)wid * 4) = make_float4(e0 / z, e1 / z, e2 / z, e3 / z);
}

// ---------------------------------------------------------------------------
// K2: u_hat via bf16 MFMA — B panel register-resident; TPB tiles' A frags
// prefetched; tail block range does the slot-scatter.
// ---------------------------------------------------------------------------
#define TPB 4
__global__ __launch_bounds__(256, 2) void k_uhat_mfma(
    const short* __restrict__ xtb, const float* __restrict__ gate,
    const short* __restrict__ Wt, const float* __restrict__ bp,
    __half* __restrict__ uh, const int* __restrict__ row,
    const int* __restrict__ col, int* __restrict__ cnt,
    int* __restrict__ slots, int* __restrict__ ovf_cnt,
    int2* __restrict__ ovf, int N, int ntiles, int E) {
  int ub = (ntiles + TPB - 1) / TPB;
  if ((int)blockIdx.x >= ub) {
    int e0 = ((blockIdx.x - ub) * 256 + threadIdx.x) * 2;
    #pragma unroll
    for (int k = 0; k < 2; ++k) {
      int e = e0 + k;
      if (e < E) {
        int c = col[e];
        int p = atomicAdd(&cnt[c], 1);
        if (p < CAP) slots[(size_t)c * CAP + p] = row[e];
        else { int q = atomicAdd(ovf_cnt, 1); ovf[q] = make_int2(c, row[e]); }
      }
    }
    return;
  }

  int lane = threadIdx.x & 63;
  int wv = threadIdx.x >> 6;
  int ri = lane & 15, kg = lane >> 4;
  int c_lo = wv * 32;

  bf16x8 bfr[4][2][4];
  float bpv[4][2];
  #pragma unroll
  for (int p = 0; p < 4; ++p)
    #pragma unroll
    for (int n2 = 0; n2 < 2; ++n2) {
      int bcol = p * 128 + c_lo + n2 * 16 + ri;
      #pragma unroll
      for (int ks = 0; ks < 4; ++ks)
        bfr[p][n2][ks] = *(const bf16x8*)(Wt + (((size_t)bcol) << 7) + ks * 32 + kg * 8);
      bpv[p][n2] = bp[bcol];
    }

  int t0 = blockIdx.x * TPB;

  bf16x8 af[TPB][4];
  #pragma unroll
  for (int tt = 0; tt < TPB; ++tt) {
    int t = t0 + tt;
    int r0 = t * 16 + ri;
    int c0 = (t < ntiles) ? ((r0 < N) ? r0 : (N - 1)) : 0;
    #pragma unroll
    for (int ks = 0; ks < 4; ++ks)
      af[tt][ks] = *(const bf16x8*)(xtb + (((size_t)c0) << 7) + ks * 32 + kg * 8);
  }

  #pragma unroll
  for (int tt = 0; tt < TPB; ++tt) {
    int t = t0 + tt;
    if (t < ntiles) {
      int m0 = t * 16;
      int rb = m0 + kg * 4;
      float gg[4][4];
      #pragma unroll
      for (int q = 0; q < 4; ++q) {
        int rm = rb + q;
        bool ok = rm < N;
        float4 gv = *(const float4*)(gate + (size_t)(ok ? rm : 0) * 4);
        gg[q][0] = ok ? gv.x : 0.f;
        gg[q][1] = ok ? gv.y : 0.f;
        gg[q][2] = ok ? gv.z : 0.f;
        gg[q][3] = ok ? gv.w : 0.f;
      }

      float fin[2][4];
      #pragma unroll
      for (int n2 = 0; n2 < 2; ++n2)
        #pragma unroll
        for (int q = 0; q < 4; ++q) fin[n2][q] = 0.f;

      #pragma unroll
      for (int p = 0; p < 4; ++p)
        #pragma unroll
        for (int n2 = 0; n2 < 2; ++n2) {
          f32x4 acc = {0.f, 0.f, 0.f, 0.f};
          #pragma unroll
          for (int ks = 0; ks < 4; ++ks)
            acc = __builtin_amdgcn_mfma_f32_16x16x32_bf16(af[tt][ks], bfr[p][n2][ks], acc, 0, 0, 0);
          #pragma unroll
          for (int q = 0; q < 4; ++q)
            fin[n2][q] += gg[q][p] * (acc[q] + bpv[p][n2]);
        }

      #pragma unroll
      for (int n2 = 0; n2 < 2; ++n2) {
        int cn = c_lo + n2 * 16 + ri;
        #pragma unroll
        for (int q = 0; q < 4; ++q) {
          int rm = rb + q;
          if (rm < N) uh[(size_t)rm * 128 + cn] = __float2half_rn(fin[n2][q]);
        }
      }
    }
  }
}

// ---------------------------------------------------------------------------
// K6: fused 3-iteration routing + squash + exp_map. One wave per node.
// Wave-uniform deg tiers: <=8 (33%, eighth-dot), <=16 (quarter-dot),
// <=32 (half-dot), >32 fallback.
// ---------------------------------------------------------------------------
__global__ __launch_bounds__(64, 4) void k_route(
    const __half* __restrict__ uh, const float* __restrict__ bias,
    const int* __restrict__ cnt, const int* __restrict__ slots,
    const int* __restrict__ ovf_cnt, const int2* __restrict__ ovf,
    int* __restrict__ fbc, int* __restrict__ claim,
    int* __restrict__ fb_rows, float* __restrict__ fb_b,
    float* __restrict__ out, int N) {
  __shared__ __align__(16) uint ssw[64];  // s as half2 words
  int lane = threadIdx.x;
  int j = blockIdx.x;
  int deg = cnt[j];
  int d0 = lane * 2;

  if (deg == 0) {
    *(float2*)(out + (size_t)j * 128 + d0) =
        make_float2((lane == 0) ? 1.f : 0.f, 0.f);
    return;
  }

  float2 bia = *(const float2*)(bias + d0);
  float s0 = 0.f, s1 = 0.f;
  const uint* uhw = (const uint*)uh;

  if (deg <= 8) {
    // ================= TINY PATH (deg <= 8, ~33%) =================
    int myrow = (lane < deg) ? slots[(size_t)j * CAP + lane] : 0;

    int e = lane >> 3, o = lane & 7;
    int er = __shfl(myrow, (e < deg) ? e : 0);
    const uint4* up = (const uint4*)(uhw + (((size_t)(uint)er) << 6) + o * 8);
    uint4 ud8[2];
    ud8[0] = up[0]; ud8[1] = up[1];

    uint g[8];
    #pragma unroll
    for (int k = 0; k < 8; ++k) {
      int rr = __builtin_amdgcn_readlane(myrow, k);
      uint v = uhw[(((size_t)(uint)rr) << 6) + lane];
      g[k] = (k < deg) ? v : 0u;
    }

    float2 uf[8];
    float a0 = 0.f, a1 = 0.f;
    #pragma unroll
    for (int k = 0; k < 8; ++k) {
      uf[k] = __half22float2(*(const __half2*)&g[k]);
      a0 += uf[k].x; a1 += uf[k].y;
    }

    float invd = 1.f / (float)deg;
    s0 = a0 * invd + bia.x;
    s1 = a1 * invd + bia.y;
    {
      float ns = s0 * s0 + s1 * s1;
      #pragma unroll
      for (int s = 32; s; s >>= 1) ns += __shfl_xor(ns, s);
      float scale = (ns / (1.f + ns)) * rsqrtf(ns + 1e-9f);
      s0 *= scale; s1 *= scale;
    }

    const uint* ssw_o = &ssw[o * 8];
    bool act = (e < deg);
    float b = 0.f;

    #pragma unroll
    for (int r = 0; r < 2; ++r) {
      __half2 sh2 = __floats2half2_rn(s0, s1);
      ssw[lane] = *(const uint*)&sh2;
      LGKM_FENCE();

      // per-edge dot: 2 b128 s-reads + 8 fdot2, 8-lane reduce
      float acc0 = 0.f, acc1 = 0.f;
      #pragma unroll
      for (int w4 = 0; w4 < 2; ++w4) {
        uint4 sw = *(const uint4*)&ssw_o[w4 * 4];
        acc0 = dot2acc(ud8[w4].x, sw.x, acc0);
        acc1 = dot2acc(ud8[w4].y, sw.y, acc1);
        acc0 = dot2acc(ud8[w4].z, sw.z, acc0);
        acc1 = dot2acc(ud8[w4].w, sw.w, acc1);
      }
      float acc = acc0 + acc1;
      acc += __shfl_xor(acc, 1);
      acc += __shfl_xor(acc, 2);
      acc += __shfl_xor(acc, 4);
      b += acc;
      float eb = act ? __expf(b) : 0.f;

      // weighted sum: single chunk of 8, dual accumulators
      float z0 = 0.f, z1 = 0.f, wa0 = 0.f, wa1 = 0.f, wb0 = 0.f, wb1 = 0.f;
      #pragma unroll
      for (int k = 0; k < 8; ++k) {
        float ev = __uint_as_float(
            __builtin_amdgcn_readlane(__float_as_uint(eb), 8 * k));
        if (k & 1) { z1 += ev; wa1 = fmaf(ev, uf[k].x, wa1); wb1 = fmaf(ev, uf[k].y, wb1); }
        else       { z0 += ev; wa0 = fmaf(ev, uf[k].x, wa0); wb0 = fmaf(ev, uf[k].y, wb0); }
      }
      float z = z0 + z1;
      float invz = 1.f / z;
      s0 = (wa0 + wa1) * invz + bia.x;
      s1 = (wb0 + wb1) * invz + bia.y;
      float ns = s0 * s0 + s1 * s1;
      #pragma unroll
      for (int s = 32; s; s >>= 1) ns += __shfl_xor(ns, s);
      float scale = (ns / (1.f + ns)) * rsqrtf(ns + 1e-9f);
      s0 *= scale; s1 *= scale;
    }
  } else if (deg <= 16) {
    // ================= FAST PATH (9..16) =================
    int myrow = (lane < deg) ? slots[(size_t)j * CAP + lane] : 0;

    int e = lane >> 2, q = lane & 3;
    int er = __shfl(myrow, (e < deg) ? e : 0);
    const uint4* up = (const uint4*)(uhw + (((size_t)(uint)er) << 6) + q * 16);
    uint4 ud4[4];
    #pragma unroll
    for (int w4 = 0; w4 < 4; ++w4) ud4[w4] = up[w4];

    uint g[16];
    #pragma unroll
    for (int c = 0; c < 16; c += 8) {
      if (c < deg) {
        #pragma unroll
        for (int k = 0; k < 8; ++k) {
          int i = c + k;
          int rr = __builtin_amdgcn_readlane(myrow, i);
          uint v = uhw[(((size_t)(uint)rr) << 6) + lane];
          g[i] = (i < deg) ? v : 0u;
        }
      }
    }

    float2 uf[16];
    float a0 = 0.f, a1 = 0.f;
    #pragma unroll
    for (int c = 0; c < 16; c += 8) {
      if (c < deg) {
        #pragma unroll
        for (int k = 0; k < 8; ++k) {
          int i = c + k;
          uf[i] = __half22float2(*(const __half2*)&g[i]);
          a0 += uf[i].x; a1 += uf[i].y;
        }
      }
    }

    float invd = 1.f / (float)deg;
    s0 = a0 * invd + bia.x;
    s1 = a1 * invd + bia.y;
    {
      float ns = s0 * s0 + s1 * s1;
      #pragma unroll
      for (int s = 32; s; s >>= 1) ns += __shfl_xor(ns, s);
      float scale = (ns / (1.f + ns)) * rsqrtf(ns + 1e-9f);
      s0 *= scale; s1 *= scale;
    }

    const uint* ssw_q = &ssw[q * 16];
    bool act = (e < deg);
    float b = 0.f;

    #pragma unroll
    for (int r = 0; r < 2; ++r) {
      __half2 sh2 = __floats2half2_rn(s0, s1);
      ssw[lane] = *(const uint*)&sh2;
      LGKM_FENCE();

      float acc0 = 0.f, acc1 = 0.f;
      #pragma unroll
      for (int w4 = 0; w4 < 4; ++w4) {
        uint4 sw = *(const uint4*)&ssw_q[w4 * 4];
        acc0 = dot2acc(ud4[w4].x, sw.x, acc0);
        acc1 = dot2acc(ud4[w4].y, sw.y, acc1);
        acc0 = dot2acc(ud4[w4].z, sw.z, acc0);
        acc1 = dot2acc(ud4[w4].w, sw.w, acc1);
      }
      float acc = acc0 + acc1;
      acc += __shfl_xor(acc, 1);
      acc += __shfl_xor(acc, 2);
      b += acc;
      float eb = act ? __expf(b) : 0.f;

      float z0 = 0.f, z1 = 0.f, wa0 = 0.f, wa1 = 0.f, wb0 = 0.f, wb1 = 0.f;
      #pragma unroll
      for (int c = 0; c < 16; c += 8) {
        if (c < deg) {
          #pragma unroll
          for (int k = 0; k < 8; ++k) {
            int i = c + k;
            float ev = __uint_as_float(
                __builtin_amdgcn_readlane(__float_as_uint(eb), 4 * i));
            if (k & 1) { z1 += ev; wa1 = fmaf(ev, uf[i].x, wa1); wb1 = fmaf(ev, uf[i].y, wb1); }
            else       { z0 += ev; wa0 = fmaf(ev, uf[i].x, wa0); wb0 = fmaf(ev, uf[i].y, wb0); }
          }
        }
      }
      float z = z0 + z1;
      float invz = 1.f / z;
      s0 = (wa0 + wa1) * invz + bia.x;
      s1 = (wb0 + wb1) * invz + bia.y;
      float ns = s0 * s0 + s1 * s1;
      #pragma unroll
      for (int s = 32; s; s >>= 1) ns += __shfl_xor(ns, s);
      float scale = (ns / (1.f + ns)) * rsqrtf(ns + 1e-9f);
      s0 *= scale; s1 *= scale;
    }
  } else if (deg <= CAP) {
    // ================= MEDIUM PATH (17..32) =================
    int myrow = (lane < deg) ? slots[(size_t)j * CAP + lane] : 0;

    int e = lane >> 1, h = lane & 1;
    int er = __shfl(myrow, (e < deg) ? e : 0);
    const uint4* up = (const uint4*)(uhw + (((size_t)(uint)er) << 6) + h * 32);
    uint4 ud[8];
    #pragma unroll
    for (int k4 = 0; k4 < 8; ++k4) ud[k4] = up[k4];

    uint g[CAP];
    #pragma unroll
    for (int c = 0; c < CAP; c += 8) {
      if (c < deg) {
        #pragma unroll
        for (int k = 0; k < 8; ++k) {
          int i = c + k;
          int rr = __builtin_amdgcn_readlane(myrow, i);
          uint v = uhw[(((size_t)(uint)rr) << 6) + lane];
          g[i] = (i < deg) ? v : 0u;
        }
      }
    }

    float a0 = 0.f, a1 = 0.f;
    #pragma unroll
    for (int c = 0; c < CAP; c += 8) {
      if (c < deg) {
        #pragma unroll
        for (int k = 0; k < 8; ++k) {
          int i = c + k;
          float2 uf = __half22float2(*(const __half2*)&g[i]);
          a0 += uf.x; a1 += uf.y;
        }
      }
    }

    float invd = 1.f / (float)deg;
    s0 = a0 * invd + bia.x;
    s1 = a1 * invd + bia.y;
    {
      float ns = s0 * s0 + s1 * s1;
      #pragma unroll
      for (int s = 32; s; s >>= 1) ns += __shfl_xor(ns, s);
      float scale = (ns / (1.f + ns)) * rsqrtf(ns + 1e-9f);
      s0 *= scale; s1 *= scale;
    }

    const uint* ssw_h = &ssw[h * 32];
    bool act = (e < deg);
    float b = 0.f;

    #pragma unroll
    for (int r = 0; r < 2; ++r) {
      __half2 sh2 = __floats2half2_rn(s0, s1);
      ssw[lane] = *(const uint*)&sh2;
      LGKM_FENCE();

      float acc0 = 0.f, acc1 = 0.f;
      #pragma unroll
      for (int k4 = 0; k4 < 8; ++k4) {
        uint4 sw = *(const uint4*)&ssw_h[k4 * 4];
        acc0 = dot2acc(ud[k4].x, sw.x, acc0);
        acc1 = dot2acc(ud[k4].y, sw.y, acc1);
        acc0 = dot2acc(ud[k4].z, sw.z, acc0);
        acc1 = dot2acc(ud[k4].w, sw.w, acc1);
      }
      float acc = acc0 + acc1;
      acc += __shfl_xor(acc, 1);
      b += acc;
      float eb = act ? __expf(b) : 0.f;

      float z0 = 0.f, z1 = 0.f, wa0 = 0.f, wa1 = 0.f, wb0 = 0.f, wb1 = 0.f;
      #pragma unroll
      for (int c = 0; c < CAP; c += 8) {
        if (c < deg) {
          #pragma unroll
          for (int k = 0; k < 8; ++k) {
            int i = c + k;
            float ev = __uint_as_float(
                __builtin_amdgcn_readlane(__float_as_uint(eb), 2 * i));
            float2 uf = __half22float2(*(const __half2*)&g[i]);
            if (k & 1) { z1 += ev; wa1 = fmaf(ev, uf.x, wa1); wb1 = fmaf(ev, uf.y, wb1); }
            else       { z0 += ev; wa0 = fmaf(ev, uf.x, wa0); wb0 = fmaf(ev, uf.y, wb0); }
          }
        }
      }
      float z = z0 + z1;
      float invz = 1.f / z;
      s0 = (wa0 + wa1) * invz + bia.x;
      s1 = (wb0 + wb1) * invz + bia.y;
      float ns = s0 * s0 + s1 * s1;
      #pragma unroll
      for (int s = 32; s; s >>= 1) ns += __shfl_xor(ns, s);
      float scale = (ns / (1.f + ns)) * rsqrtf(ns + 1e-9f);
      s0 *= scale; s1 *= scale;
    }
  } else {
    // ================= FALLBACK (deg > 32, ~never) =================
    int base = 0;
    if (lane == 0) base = atomicAdd(claim, deg);
    base = __shfl(base, 0);
    int* mr = fb_rows + base;
    float* b = fb_b + base;
    if (lane < CAP) mr[lane] = slots[(size_t)j * CAP + lane];
    int novf = *ovf_cnt;
    for (int t = lane; t < novf; t += 64) {
      int2 ov = ovf[t];
      if (ov.x == j) {
        int p = atomicAdd(&fbc[j], 1);
        mr[CAP + p] = ov.y;
      }
    }
    asm volatile("s_waitcnt vmcnt(0)" ::: "memory");

    const __half2* uh2 = (const __half2*)uh;
    for (int i = lane; i < deg; i += 64) atomicExch(&b[i], 0.f);
    asm volatile("s_waitcnt vmcnt(0)" ::: "memory");

    for (int r = 0; r < 3; ++r) {
      float mx = -3.4e38f;
      for (int i = lane; i < deg; i += 64)
        mx = fmaxf(mx, atomicAdd(&b[i], 0.f));
      #pragma unroll
      for (int s = 32; s; s >>= 1) mx = fmaxf(mx, __shfl_xor(mx, s));
      float z = 0.f;
      for (int i = lane; i < deg; i += 64) z += expf(atomicAdd(&b[i], 0.f) - mx);
      #pragma unroll
      for (int s = 32; s; s >>= 1) z += __shfl_xor(z, s);
      float invz = 1.f / z;

      s0 = 0.f; s1 = 0.f;
      for (int i = 0; i < deg; ++i) {
        float c = expf(atomicAdd(&b[i], 0.f) - mx) * invz;
        int rr = mr[i];
        float2 uf = __half22float2(uh2[(((size_t)rr) << 6) + lane]);
        s0 = fmaf(c, uf.x, s0);
        s1 = fmaf(c, uf.y, s1);
      }
      s0 += bia.x; s1 += bia.y;

      float ns = s0 * s0 + s1 * s1;
      #pragma unroll
      for (int s = 32; s; s >>= 1) ns += __shfl_xor(ns, s);
      float scale = (ns / (1.f + ns)) * rsqrtf(ns + 1e-9f);
      s0 *= scale; s1 *= scale;

      if (r < 2) {
        for (int i = 0; i < deg; ++i) {
          int rr = mr[i];
          float2 uf = __half22float2(uh2[(((size_t)rr) << 6) + lane]);
          float pp = s0 * uf.x + s1 * uf.y;
          #pragma unroll
          for (int s = 32; s; s >>= 1) pp += __shfl_xor(pp, s);
          if (lane == 0) atomicAdd(&b[i], pp);
        }
        asm volatile("s_waitcnt vmcnt(0)" ::: "memory");
      }
    }
  }

  // exp_map(s, ref)
  float pn = s0 * s0 + s1 * s1;
  if (lane == 0) pn -= 2.f * s0 * s0;
  #pragma unroll
  for (int s = 32; s; s >>= 1) pn += __shfl_xor(pn, s);
  float vn = fminf(sqrtf(fabsf(pn) + 1e-12f), 10.f);
  float sh = sinhf(vn) / vn;
  float ov0 = sh * s0 + ((lane == 0) ? coshf(vn) : 0.f);
  float ov1 = sh * s1;
  *(float2*)(out + (size_t)j * 128 + d0) = make_float2(ov0, ov1);
}

// ---------------------------------------------------------------------------
extern "C" void kernel_launch(void* const* d_in, const int* in_sizes, int n_in,
                              void* d_out, int out_size, void* d_ws, size_t ws_size,
                              hipStream_t stream) {
  const float* x    = (const float*)d_in[0];
  const int*   ei   = (const int*)d_in[1];
  const float* Wp   = (const float*)d_in[2];
  const float* bp   = (const float*)d_in[3];
  const float* Wg   = (const float*)d_in[4];
  const float* bg   = (const float*)d_in[5];
  const float* bias = (const float*)d_in[6];
  float* out = (float*)d_out;

  int N = in_sizes[0] / 128;
  int E = in_sizes[1] / 2;
  const int* row = ei;
  const int* col = ei + E;

  __hip_bfloat16* xtb = (__hip_bfloat16*)d_ws;                  // N*128 bf16
  __half* uhh = (__half*)(xtb + (size_t)N * 128);               // N*128 f16
  float* gate = (float*)(uhh + (size_t)N * 128);                // N*4 f32
  __hip_bfloat16* Wt = (__hip_bfloat16*)(gate + (size_t)N * 4); // 512*128 bf16
  int* cnt = (int*)(Wt + 512 * 128);                            // N
  int* fbc = cnt + N;                                           // N
  int* claim = fbc + N;                                         // 1
  int* ovf_cnt = claim + 1;                                     // 1
  int* slots = ovf_cnt + 1;                                     // N*CAP
  int2* ovf = (int2*)(slots + (size_t)N * CAP);                 // E int2
  int* fb_rows = (int*)(ovf + E);                               // E
  float* fb_b = (float*)(fb_rows + E);                          // E

  int tb = (N + 3) / 4;
  int hb = (E + 511) / 512;
  int nz = 2 * N + 2;
  int zb = (nz + 255) / 256;
  int ntiles = (N + 15) / 16;
  int ub = (ntiles + TPB - 1) / TPB;
  k_tangent_gate<<<tb + 256 + zb, 256, 0, stream>>>(
      x, Wg, bg, xtb, gate, Wp, Wt, cnt, nz, N);
  k_uhat_mfma<<<ub + hb, 256, 0, stream>>>(
      (const short*)xtb, gate, (const short*)Wt, bp, uhh,
      row, col, cnt, slots, ovf_cnt, ovf, N, ntiles, E);
  k_route<<<N, 64, 0, stream>>>(
      uhh, bias, cnt, slots, ovf_cnt, ovf, fbc, claim, fb_rows, fb_b, out, N);
}